// Round 1
// baseline (461.157 us; speedup 1.0000x reference)
//
#include <hip/hip_runtime.h>

typedef unsigned short USHORT;
typedef short bf16x8 __attribute__((ext_vector_type(8)));
typedef float f32x4 __attribute__((ext_vector_type(4)));

__device__ __forceinline__ USHORT f2bf(float f) {
    unsigned u = __float_as_uint(f);
    u += 0x7fffu + ((u >> 16) & 1u);   // RNE, no NaNs in this problem
    return (USHORT)(u >> 16);
}
__device__ __forceinline__ float bf2f(USHORT s) {
    return __uint_as_float(((unsigned)s) << 16);
}
__device__ __forceinline__ float sigm(float v) { return 1.f / (1.f + __expf(-v)); }
__device__ __forceinline__ float mytanh(float v) { return 1.f - 2.f / (__expf(2.f * v) + 1.f); }

using gcu32p = const unsigned int __attribute__((address_space(1))) *;
using lu32p  = unsigned int __attribute__((address_space(3))) *;

__device__ __forceinline__ void load_lds16(const void* g, void* l) {
    __builtin_amdgcn_global_load_lds((gcu32p)g, (lu32p)l, 16, 0, 0);
}

// ---- single conversion kernel: fp32 sources -> bf16 A [8192x4096] and W [3072x4096]
__global__ __launch_bounds__(256) void conv_all(const float* __restrict__ h,
                                                const float* __restrict__ x,
                                                const float* __restrict__ glo,
                                                const float* __restrict__ Wi,
                                                const float* __restrict__ Wf,
                                                const float* __restrict__ Wc,
                                                USHORT* __restrict__ A,
                                                USHORT* __restrict__ W) {
    int bid = blockIdx.x;
    if (bid < 16384) {
        int idx = (bid * 256 + threadIdx.x) * 8;      // [0, 8192*4096)
        int m = idx >> 12, k = idx & 4095;
        const float* s;
        if (k < 1024)      s = h   + (size_t)m * 1024 + k;
        else if (k < 3072) s = x   + (size_t)m * 2048 + (k - 1024);
        else               s = glo + (size_t)m * 1024 + (k - 3072);
        float4 f0 = ((const float4*)s)[0];
        float4 f1 = ((const float4*)s)[1];
        union { USHORT us[8]; uint4 v; } u;
        u.us[0] = f2bf(f0.x); u.us[1] = f2bf(f0.y); u.us[2] = f2bf(f0.z); u.us[3] = f2bf(f0.w);
        u.us[4] = f2bf(f1.x); u.us[5] = f2bf(f1.y); u.us[6] = f2bf(f1.z); u.us[7] = f2bf(f1.w);
        *(uint4*)(A + idx) = u.v;
    } else {
        int idx = ((bid - 16384) * 256 + threadIdx.x) * 8;   // [0, 3072*4096)
        int n = idx >> 12, k = idx & 4095;
        const float* base = (n < 1024) ? Wi : (n < 2048 ? Wf : Wc);
        const float* s = base + (size_t)(n & 1023) * 4096 + k;
        float4 f0 = ((const float4*)s)[0];
        float4 f1 = ((const float4*)s)[1];
        union { USHORT us[8]; uint4 v; } u;
        u.us[0] = f2bf(f0.x); u.us[1] = f2bf(f0.y); u.us[2] = f2bf(f0.z); u.us[3] = f2bf(f0.w);
        u.us[4] = f2bf(f1.x); u.us[5] = f2bf(f1.y); u.us[6] = f2bf(f1.z); u.us[7] = f2bf(f1.w);
        *(uint4*)(W + idx) = u.v;
    }
}

// ============================================================================
// 8-phase 256x192 GEMM (T1+T2+T3+T4+T5): gates[8192,3072] = A[8192,4096]@W^T+b
//
// BM=256 BN=192 BK=64, 512 thr = 8 waves (2M x 4N), per-wave 128x48 out,
// LDS = 2buf x (256+192) x 64 bf16 = 112 KiB -> 1 block/CU.
// Per K-tile: 4 phases of {ds-read subtile | issue 1 staging chunk ->
//   sched_barrier(0) -> s_barrier -> setprio(1) -> 12 MFMA -> setprio(0) ->
//   s_barrier}; end-of-tile s_waitcnt vmcnt(3) BEFORE the closing barrier.
// Issue slots (tile t): p0/p1: A(t+1) [4 chunks, other parity; WAR-safe vs
//   t-1 A last read at t-1p3], p2/p3: B(t+2) [3 chunks, same parity; WAR-safe:
//   bv of tile t read only at p0, drained by p0 mid-barrier].
// Queue at each tile end: [B(t+1)x3, A(t+1)x4, B(t+2)x3]; vmcnt(3) lands
//   exactly through A(t+1) (tile t+1 complete), 3 loads stay in flight.
// Tail: tile 62 ends vmcnt(0); tile 63 no issues/waits.
// LDS granule swizzle (both sides): granule pos p of row r holds global
//   granule p ^ ((r>>1)&7)  -> conflict-free ds_read_b128 (same as verified
//   predecessor: SQ_LDS_BANK_CONFLICT == 0).
// ============================================================================

#define A_ELEMS 16384   // 256*64 per parity
#define B_ELEMS 12288   // 192*64 per parity

template<int AISS, int BISS, int WMODE>   // WMODE 0: vmcnt(3), 1: vmcnt(0), 2: none
__device__ __forceinline__ void do_tile(int par, USHORT* As, USHORT* Bs,
                                        const USHORT* (&aG)[4], const USHORT* (&bG)[3],
                                        int wvOff, int aOff, int bOff, int koff0,
                                        f32x4 (&acc)[8][3]) {
    const USHORT* aRdp = As + par * A_ELEMS + aOff;
    const USHORT* bRdp = Bs + par * B_ELEMS + bOff;
    bf16x8 bv[3][2];
    #pragma unroll
    for (int q = 0; q < 4; ++q) {
        bf16x8 av[2][2];
        #pragma unroll
        for (int m2 = 0; m2 < 2; ++m2)
            #pragma unroll
            for (int kh = 0; kh < 2; ++kh)
                av[m2][kh] = *(const bf16x8*)(aRdp + (q * 32 + m2 * 16) * 64 + (koff0 ^ (kh * 32)));
        if (q == 0) {
            #pragma unroll
            for (int nt = 0; nt < 3; ++nt)
                #pragma unroll
                for (int kh = 0; kh < 2; ++kh)
                    bv[nt][kh] = *(const bf16x8*)(bRdp + nt * 16 * 64 + (koff0 ^ (kh * 32)));
        }
        if (AISS && q < 2) {            // stage A(t+1) into other parity
            int j = q * 2;
            load_lds16(aG[j],     As + (par ^ 1) * A_ELEMS + j * 4096 + wvOff);
            load_lds16(aG[j + 1], As + (par ^ 1) * A_ELEMS + (j + 1) * 4096 + wvOff);
            aG[j] += 64; aG[j + 1] += 64;
        }
        if (BISS && q == 2) {           // stage B(t+2) into current parity
            load_lds16(bG[0], Bs + par * B_ELEMS + 0    + wvOff);
            load_lds16(bG[1], Bs + par * B_ELEMS + 4096 + wvOff);
            bG[0] += 64; bG[1] += 64;
        }
        if (BISS && q == 3) {
            load_lds16(bG[2], Bs + par * B_ELEMS + 8192 + wvOff);
            bG[2] += 64;
        }
        __builtin_amdgcn_sched_barrier(0);
        __builtin_amdgcn_s_barrier();
        __builtin_amdgcn_s_setprio(1);
        #pragma unroll
        for (int m2 = 0; m2 < 2; ++m2)
            #pragma unroll
            for (int nt = 0; nt < 3; ++nt)
                #pragma unroll
                for (int kh = 0; kh < 2; ++kh)
                    acc[q * 2 + m2][nt] = __builtin_amdgcn_mfma_f32_16x16x32_bf16(
                        av[m2][kh], bv[nt][kh], acc[q * 2 + m2][nt], 0, 0, 0);
        __builtin_amdgcn_s_setprio(0);
        if (q == 3) {
            if (WMODE == 0) asm volatile("s_waitcnt vmcnt(3)" ::: "memory");
            else if (WMODE == 1) asm volatile("s_waitcnt vmcnt(0)" ::: "memory");
        }
        __builtin_amdgcn_s_barrier();
    }
}

__global__ __launch_bounds__(512, 2) void gemm8p(const USHORT* __restrict__ A,
                                                 const USHORT* __restrict__ B,
                                                 const float* __restrict__ bi,
                                                 const float* __restrict__ bfp,
                                                 const float* __restrict__ bc,
                                                 USHORT* __restrict__ gates) {
    __shared__ __align__(16) USHORT As[2 * 256 * 64];   // 64 KiB
    __shared__ __align__(16) USHORT Bs[2 * 192 * 64];   // 48 KiB

    const int tid  = threadIdx.x;
    const int lane = tid & 63, wv = tid >> 6;
    // XCD-aware bijective swizzle (512 % 8 == 0). Per XCD per round: one
    // n-panel (1.5 MiB B -> L2-resident) x 32 m-blocks.
    const int s  = (blockIdx.x & 7) * 64 + (blockIdx.x >> 3);
    const int m0 = (s & 31) * 256;
    const int n0 = (s >> 5) * 192;

    const int wM = wv >> 2, wN = wv & 3;    // 2 x 4 wave grid
    const int lm = lane & 15;
    const int gw = lane >> 4;
    const int koff0 = ((gw ^ (lm >> 1)) & 7) * 8;   // read-side swizzled k-granule (elems)
    const int wvOff = wv * 512;                     // staging LDS offset (elems)
    const int aOff = (wM * 128 + lm) * 64;
    const int bOff = (wN * 48 + lm) * 64;

    // staging: chunk covers 64 panel rows; wave wv takes rows wv*8+(l>>3);
    // LDS pos p = l&7, fetch global granule p ^ ((r>>1)&7) = (l&7) ^ (4*(wv&1) + (l>>4)).
    const int gswz = ((lane & 7) ^ (4 * (wv & 1) + (lane >> 4))) & 7;
    const USHORT* aG[4];
    const USHORT* bG[3];
    #pragma unroll
    for (int j = 0; j < 4; ++j)
        aG[j] = A + (size_t)(m0 + j * 64 + wv * 8 + (lane >> 3)) * 4096 + gswz * 8;
    #pragma unroll
    for (int t = 0; t < 3; ++t)
        bG[t] = B + (size_t)(n0 + t * 64 + wv * 8 + (lane >> 3)) * 4096 + gswz * 8;

    f32x4 acc[8][3];
    #pragma unroll
    for (int a = 0; a < 8; ++a)
        #pragma unroll
        for (int b = 0; b < 3; ++b) {
            f32x4 z = {0.f, 0.f, 0.f, 0.f};
            acc[a][b] = z;
        }

    // prologue: A(0), B(0), B(1); wait until tile 0 complete (B(1) in flight)
    #pragma unroll
    for (int j = 0; j < 4; ++j) { load_lds16(aG[j], As + j * 4096 + wvOff); aG[j] += 64; }
    #pragma unroll
    for (int t = 0; t < 3; ++t) { load_lds16(bG[t], Bs + t * 4096 + wvOff); bG[t] += 64; }
    #pragma unroll
    for (int t = 0; t < 3; ++t) { load_lds16(bG[t], Bs + B_ELEMS + t * 4096 + wvOff); bG[t] += 64; }
    asm volatile("s_waitcnt vmcnt(3)" ::: "memory");
    __builtin_amdgcn_s_barrier();

    #pragma unroll 2
    for (int kt = 0; kt < 62; ++kt)
        do_tile<1, 1, 0>(kt & 1, As, Bs, aG, bG, wvOff, aOff, bOff, koff0, acc);
    do_tile<1, 0, 1>(0, As, Bs, aG, bG, wvOff, aOff, bOff, koff0, acc);   // kt=62
    do_tile<0, 0, 2>(1, As, Bs, aG, bG, wvOff, aOff, bOff, koff0, acc);   // kt=63

    // epilogue: +bias, store bf16 gates. C/D: col = lane&15, row = (lane>>4)*4 + r.
    #pragma unroll
    for (int nt = 0; nt < 3; ++nt) {
        int gc = n0 + wN * 48 + nt * 16 + lm;
        float bb = (gc < 1024) ? bi[gc] : (gc < 2048 ? bfp[gc - 1024] : bc[gc - 2048]);
        #pragma unroll
        for (int mt = 0; mt < 8; ++mt) {
            #pragma unroll
            for (int r = 0; r < 4; ++r) {
                int lrow = wM * 128 + mt * 16 + (lane >> 4) * 4 + r;
                gates[(size_t)(m0 + lrow) * 3072 + gc] = f2bf(acc[mt][nt][r] + bb);
            }
        }
    }
}

// ---- elementwise epilogue: out = alpha*c + (1-alpha)*h
__global__ __launch_bounds__(256) void epi(const USHORT* __restrict__ gates,
                                           const float* __restrict__ h,
                                           float* __restrict__ out) {
    int e = (blockIdx.x * 256 + threadIdx.x) * 8;   // [0, 8192*1024)
    int m = e >> 10, n = e & 1023;
    const USHORT* gp = gates + (size_t)m * 3072 + n;
    union { USHORT us[8]; uint4 v; } gi, gf, gc;
    gi.v = *(const uint4*)(gp);
    gf.v = *(const uint4*)(gp + 1024);
    gc.v = *(const uint4*)(gp + 2048);
    const float* hp = h + (size_t)m * 1024 + n;
    float4 h0 = ((const float4*)hp)[0];
    float4 h1 = ((const float4*)hp)[1];
    float hv[8] = {h0.x, h0.y, h0.z, h0.w, h1.x, h1.y, h1.z, h1.w};
    float o[8];
    #pragma unroll
    for (int j = 0; j < 8; ++j) {
        float iv = sigm(bf2f(gi.us[j]));
        float fv = sigm(bf2f(gf.us[j]));
        float cv = mytanh(bf2f(gc.us[j]));
        float al = sigm(iv - fv);
        o[j] = al * cv + (1.f - al) * hv[j];
    }
    float4* op = (float4*)(out + (size_t)m * 1024 + n);
    op[0] = make_float4(o[0], o[1], o[2], o[3]);
    op[1] = make_float4(o[4], o[5], o[6], o[7]);
}

// ---- fallback: fused 3-phase kernel, register-convert staging (only if ws too small)
__global__ __launch_bounds__(256) void gemm3_noconv(const float* __restrict__ h,
                                                    const float* __restrict__ x,
                                                    const float* __restrict__ glo,
                                                    const float* __restrict__ Wi,
                                                    const float* __restrict__ Wf,
                                                    const float* __restrict__ Wc,
                                                    const float* __restrict__ bi,
                                                    const float* __restrict__ bfp,
                                                    const float* __restrict__ bc,
                                                    float* __restrict__ out) {
    __shared__ USHORT At[128 * 32];
    __shared__ USHORT Bt[128 * 32];
    __shared__ USHORT stash[128 * 136];

    const int tid  = threadIdx.x;
    const int lane = tid & 63, wv = tid >> 6;
    const int n0 = blockIdx.x * 128;
    const int m0 = blockIdx.y * 128;
    const int wM = wv >> 1, wN = wv & 1;
    const int lm = lane & 15, qk = (lane >> 4) * 8;
    const int rowS = tid >> 1;
    const int colS = (tid & 1) * 16;

    for (int p = 0; p < 3; ++p) {
        f32x4 acc[4][4];
        #pragma unroll
        for (int a = 0; a < 4; ++a)
            #pragma unroll
            for (int b = 0; b < 4; ++b) {
                f32x4 z = {0.f, 0.f, 0.f, 0.f};
                acc[a][b] = z;
            }
        const float* Wg = (p == 0) ? Wi : (p == 1 ? Wf : Wc);

        for (int kt = 0; kt < 128; ++kt) {
            __syncthreads();
            int k = kt * 32 + colS;
            const float* s;
            if (k < 1024)      s = h   + (size_t)(m0 + rowS) * 1024 + k;
            else if (k < 3072) s = x   + (size_t)(m0 + rowS) * 2048 + (k - 1024);
            else               s = glo + (size_t)(m0 + rowS) * 1024 + (k - 3072);
            float4 f0 = ((const float4*)s)[0], f1 = ((const float4*)s)[1];
            float4 f2 = ((const float4*)s)[2], f3 = ((const float4*)s)[3];
            union { USHORT us[8]; uint4 v; } u0, u1;
            u0.us[0]=f2bf(f0.x); u0.us[1]=f2bf(f0.y); u0.us[2]=f2bf(f0.z); u0.us[3]=f2bf(f0.w);
            u0.us[4]=f2bf(f1.x); u0.us[5]=f2bf(f1.y); u0.us[6]=f2bf(f1.z); u0.us[7]=f2bf(f1.w);
            u1.us[0]=f2bf(f2.x); u1.us[1]=f2bf(f2.y); u1.us[2]=f2bf(f2.z); u1.us[3]=f2bf(f2.w);
            u1.us[4]=f2bf(f3.x); u1.us[5]=f2bf(f3.y); u1.us[6]=f2bf(f3.z); u1.us[7]=f2bf(f3.w);
            *(uint4*)(At + rowS * 32 + colS)     = u0.v;
            *(uint4*)(At + rowS * 32 + colS + 8) = u1.v;
            const float* sw = Wg + (size_t)(n0 + rowS) * 4096 + k;
            float4 w0 = ((const float4*)sw)[0], w1 = ((const float4*)sw)[1];
            float4 w2 = ((const float4*)sw)[2], w3 = ((const float4*)sw)[3];
            union { USHORT us[8]; uint4 v; } v0, v1;
            v0.us[0]=f2bf(w0.x); v0.us[1]=f2bf(w0.y); v0.us[2]=f2bf(w0.z); v0.us[3]=f2bf(w0.w);
            v0.us[4]=f2bf(w1.x); v0.us[5]=f2bf(w1.y); v0.us[6]=f2bf(w1.z); v0.us[7]=f2bf(w1.w);
            v1.us[0]=f2bf(w2.x); v1.us[1]=f2bf(w2.y); v1.us[2]=f2bf(w2.z); v1.us[3]=f2bf(w2.w);
            v1.us[4]=f2bf(w3.x); v1.us[5]=f2bf(w3.y); v1.us[6]=f2bf(w3.z); v1.us[7]=f2bf(w3.w);
            *(uint4*)(Bt + rowS * 32 + colS)     = v0.v;
            *(uint4*)(Bt + rowS * 32 + colS + 8) = v1.v;
            __syncthreads();

            bf16x8 av[4], bv[4];
            #pragma unroll
            for (int mt = 0; mt < 4; ++mt)
                av[mt] = *(const bf16x8*)(At + (wM * 64 + mt * 16 + lm) * 32 + qk);
            #pragma unroll
            for (int nt = 0; nt < 4; ++nt)
                bv[nt] = *(const bf16x8*)(Bt + (wN * 64 + nt * 16 + lm) * 32 + qk);
            #pragma unroll
            for (int mt = 0; mt < 4; ++mt)
                #pragma unroll
                for (int nt = 0; nt < 4; ++nt)
                    acc[mt][nt] = __builtin_amdgcn_mfma_f32_16x16x32_bf16(
                        av[mt], bv[nt], acc[mt][nt], 0, 0, 0);
        }

        const float* bias = (p == 0) ? bi : (p == 1 ? bfp : bc);
        #pragma unroll
        for (int nt = 0; nt < 4; ++nt) {
            int lcol = wN * 64 + nt * 16 + lm;
            float bb = bias[n0 + lcol];
            #pragma unroll
            for (int mt = 0; mt < 4; ++mt) {
                #pragma unroll
                for (int r = 0; r < 4; ++r) {
                    int lrow = wM * 64 + mt * 16 + (lane >> 4) * 4 + r;
                    float g = acc[mt][nt][r] + bb;
                    int li = lrow * 136 + lcol;
                    if (p == 0) {
                        stash[li] = f2bf(sigm(g));
                    } else if (p == 1) {
                        float iv = bf2f(stash[li]);
                        stash[li] = f2bf(sigm(iv - sigm(g)));
                    } else {
                        float al = bf2f(stash[li]);
                        float cv = mytanh(g);
                        size_t gi = (size_t)(m0 + lrow) * 1024 + (n0 + lcol);
                        out[gi] = al * cv + (1.f - al) * h[gi];
                    }
                }
            }
        }
    }
}

extern "C" void kernel_launch(void* const* d_in, const int* in_sizes, int n_in,
                              void* d_out, int out_size, void* d_ws, size_t ws_size,
                              hipStream_t stream) {
    const float* h   = (const float*)d_in[0];
    const float* x   = (const float*)d_in[1];
    const float* glo = (const float*)d_in[2];
    const float* Wi  = (const float*)d_in[3];
    const float* bi  = (const float*)d_in[4];
    const float* Wf  = (const float*)d_in[5];
    const float* bfp = (const float*)d_in[6];
    const float* Wc  = (const float*)d_in[7];
    const float* bc  = (const float*)d_in[8];
    float* out = (float*)d_out;

    const size_t szA = (size_t)8192 * 4096 * 2;   // 64 MiB bf16 A
    const size_t szW = (size_t)3072 * 4096 * 2;   // 24 MiB bf16 W
    const size_t szG = (size_t)8192 * 3072 * 2;   // 48 MiB bf16 gates

    if (ws_size >= szA + szW + szG) {
        USHORT* Abf = (USHORT*)d_ws;
        USHORT* Wbf = (USHORT*)((char*)d_ws + szA);
        USHORT* Gbf = (USHORT*)((char*)d_ws + szA + szW);
        conv_all<<<16384 + 6144, 256, 0, stream>>>(h, x, glo, Wi, Wf, Wc, Abf, Wbf);
        gemm8p<<<512, 512, 0, stream>>>(Abf, Wbf, bi, bfp, bc, Gbf);
        epi<<<4096, 256, 0, stream>>>(Gbf, h, out);
    } else {
        gemm3_noconv<<<dim3(8, 64), 256, 0, stream>>>(
            h, x, glo, Wi, Wf, Wc, bi, bfp, bc, out);
    }
}

// Round 2
// 448.218 us; speedup vs baseline: 1.0289x; 1.0289x over previous
//
#include <hip/hip_runtime.h>

typedef unsigned short USHORT;
typedef short bf16x8 __attribute__((ext_vector_type(8)));
typedef float f32x4 __attribute__((ext_vector_type(4)));

__device__ __forceinline__ USHORT f2bf(float f) {
    unsigned u = __float_as_uint(f);
    u += 0x7fffu + ((u >> 16) & 1u);   // RNE, no NaNs in this problem
    return (USHORT)(u >> 16);
}
__device__ __forceinline__ float bf2f(USHORT s) {
    return __uint_as_float(((unsigned)s) << 16);
}
__device__ __forceinline__ float sigm(float v) { return 1.f / (1.f + __expf(-v)); }
__device__ __forceinline__ float mytanh(float v) { return 1.f - 2.f / (__expf(2.f * v) + 1.f); }

using gcu32p = const unsigned int __attribute__((address_space(1))) *;
using lu32p  = unsigned int __attribute__((address_space(3))) *;

__device__ __forceinline__ void load_lds16(const void* g, void* l) {
    __builtin_amdgcn_global_load_lds((gcu32p)g, (lu32p)l, 16, 0, 0);
}

// ---- single conversion kernel: fp32 sources -> bf16 A [8192x4096] and W [3072x4096]
__global__ __launch_bounds__(256) void conv_all(const float* __restrict__ h,
                                                const float* __restrict__ x,
                                                const float* __restrict__ glo,
                                                const float* __restrict__ Wi,
                                                const float* __restrict__ Wf,
                                                const float* __restrict__ Wc,
                                                USHORT* __restrict__ A,
                                                USHORT* __restrict__ W) {
    int bid = blockIdx.x;
    if (bid < 16384) {
        int idx = (bid * 256 + threadIdx.x) * 8;      // [0, 8192*4096)
        int m = idx >> 12, k = idx & 4095;
        const float* s;
        if (k < 1024)      s = h   + (size_t)m * 1024 + k;
        else if (k < 3072) s = x   + (size_t)m * 2048 + (k - 1024);
        else               s = glo + (size_t)m * 1024 + (k - 3072);
        float4 f0 = ((const float4*)s)[0];
        float4 f1 = ((const float4*)s)[1];
        union { USHORT us[8]; uint4 v; } u;
        u.us[0] = f2bf(f0.x); u.us[1] = f2bf(f0.y); u.us[2] = f2bf(f0.z); u.us[3] = f2bf(f0.w);
        u.us[4] = f2bf(f1.x); u.us[5] = f2bf(f1.y); u.us[6] = f2bf(f1.z); u.us[7] = f2bf(f1.w);
        *(uint4*)(A + idx) = u.v;
    } else {
        int idx = ((bid - 16384) * 256 + threadIdx.x) * 8;   // [0, 3072*4096)
        int n = idx >> 12, k = idx & 4095;
        const float* base = (n < 1024) ? Wi : (n < 2048 ? Wf : Wc);
        const float* s = base + (size_t)(n & 1023) * 4096 + k;
        float4 f0 = ((const float4*)s)[0];
        float4 f1 = ((const float4*)s)[1];
        union { USHORT us[8]; uint4 v; } u;
        u.us[0] = f2bf(f0.x); u.us[1] = f2bf(f0.y); u.us[2] = f2bf(f0.z); u.us[3] = f2bf(f0.w);
        u.us[4] = f2bf(f1.x); u.us[5] = f2bf(f1.y); u.us[6] = f2bf(f1.z); u.us[7] = f2bf(f1.w);
        *(uint4*)(W + idx) = u.v;
    }
}

// ============================================================================
// 8-phase 256x192 GEMM, DEEP pipeline (2-tile prefetch both operands):
//   gates[8192,3072] = A[8192,4096] @ W[3072,4096]^T + bias    (bf16 in/out)
//
// BM=256 BN=192 BK=64, 512 thr = 8 waves (2M x 4N), per-wave 128x48 out.
// LDS: A triple-buffer (3 x 32 KiB) + B double-buffer (2 x 24 KiB) = 144 KiB
//   -> 1 block/CU; latency hiding comes from pipeline depth, not TLP.
// Tile t, 4 phases, each {4-10 ds_read_b128 | issue staging -> s_barrier ->
//   setprio(1) -> 12 MFMA -> setprio(0) -> [q3: vmcnt(7)] -> s_barrier}:
//   p0/p1: issue A(t+2) into buf (t+2)%3  (last read at t-1 -> WAR-safe)
//   p2/p3: issue B(t+2) into buf t&1      (bv reads drained at p0 barrier)
// End-of-tile queue = [A(t+1)x4, B(t+1)x3, A(t+2)x4, B(t+2)x3]; vmcnt(7)
//   retires exactly through B(t+1); 7 loads stay in flight; issue->wait
//   cover ~7 phases (vs 3 in the shallow version that stalled at 35% Mfma).
// Prologue: stage A0,B0,A1,B1 (14 loads), vmcnt(7). Tails: t=62 vmcnt(0),
//   t=63 no wait. Buffer rotation via named-pointer swap (no runtime-indexed
//   arrays -> no scratch).
// LDS granule swizzle (both sides, verified-correct in prior round): pos p of
//   row r holds global granule p ^ ((r>>1)&7) -> conflict-free ds_read_b128.
// ============================================================================

#define A_ELEMS 16384   // 256*64 per buffer
#define B_ELEMS 12288   // 192*64 per buffer

template<int ISS, int WMODE>   // WMODE 0: vmcnt(7), 1: vmcnt(0), 2: none
__device__ __forceinline__ void do_tile(const USHORT* aRd, const USHORT* bRd,
                                        USHORT* aWr, USHORT* bWr,
                                        const USHORT* (&aG)[4], const USHORT* (&bG)[3],
                                        int koff0, f32x4 (&acc)[8][3]) {
    bf16x8 bv[3][2];
    #pragma unroll
    for (int q = 0; q < 4; ++q) {
        bf16x8 av[2][2];
        #pragma unroll
        for (int m2 = 0; m2 < 2; ++m2)
            #pragma unroll
            for (int kh = 0; kh < 2; ++kh)
                av[m2][kh] = *(const bf16x8*)(aRd + (q * 32 + m2 * 16) * 64 + (koff0 ^ (kh * 32)));
        if (q == 0) {
            #pragma unroll
            for (int nt = 0; nt < 3; ++nt)
                #pragma unroll
                for (int kh = 0; kh < 2; ++kh)
                    bv[nt][kh] = *(const bf16x8*)(bRd + nt * 16 * 64 + (koff0 ^ (kh * 32)));
        }
        if (ISS) {
            if (q == 0) {            // stage A(t+2) into rotation buffer
                load_lds16(aG[0], aWr);
                load_lds16(aG[1], aWr + 4096);
                aG[0] += 64; aG[1] += 64;
            } else if (q == 1) {
                load_lds16(aG[2], aWr + 8192);
                load_lds16(aG[3], aWr + 12288);
                aG[2] += 64; aG[3] += 64;
            } else if (q == 2) {     // stage B(t+2) into same-parity buffer
                load_lds16(bG[0], bWr);
                load_lds16(bG[1], bWr + 4096);
                bG[0] += 64; bG[1] += 64;
            } else {
                load_lds16(bG[2], bWr + 8192);
                bG[2] += 64;
            }
        }
        __builtin_amdgcn_sched_barrier(0);
        __builtin_amdgcn_s_barrier();
        __builtin_amdgcn_s_setprio(1);
        #pragma unroll
        for (int m2 = 0; m2 < 2; ++m2)
            #pragma unroll
            for (int nt = 0; nt < 3; ++nt)
                #pragma unroll
                for (int kh = 0; kh < 2; ++kh)
                    acc[q * 2 + m2][nt] = __builtin_amdgcn_mfma_f32_16x16x32_bf16(
                        av[m2][kh], bv[nt][kh], acc[q * 2 + m2][nt], 0, 0, 0);
        __builtin_amdgcn_s_setprio(0);
        if (q == 3) {
            if (WMODE == 0) asm volatile("s_waitcnt vmcnt(7)" ::: "memory");
            else if (WMODE == 1) asm volatile("s_waitcnt vmcnt(0)" ::: "memory");
        }
        __builtin_amdgcn_s_barrier();
    }
}

__global__ __launch_bounds__(512, 2) void gemm8p(const USHORT* __restrict__ A,
                                                 const USHORT* __restrict__ B,
                                                 const float* __restrict__ bi,
                                                 const float* __restrict__ bfp,
                                                 const float* __restrict__ bc,
                                                 USHORT* __restrict__ gates) {
    __shared__ __align__(16) USHORT As[3 * 256 * 64];   // 96 KiB (triple buffer)
    __shared__ __align__(16) USHORT Bs[2 * 192 * 64];   // 48 KiB (double buffer)

    const int tid  = threadIdx.x;
    const int lane = tid & 63, wv = tid >> 6;
    // XCD-aware bijective swizzle (512 % 8 == 0). Per XCD: 2 n-panels x 32
    // m-blocks; B panel (1.5 MiB) is L2-resident -> B fetched once chip-wide
    // (confirmed: FETCH = 8x64 MiB A + 24 MiB B).
    const int s  = (blockIdx.x & 7) * 64 + (blockIdx.x >> 3);
    const int m0 = (s & 31) * 256;
    const int n0 = (s >> 5) * 192;

    const int wM = wv >> 2, wN = wv & 3;    // 2 x 4 wave grid
    const int lm = lane & 15;
    const int gw = lane >> 4;
    const int koff0 = ((gw ^ (lm >> 1)) & 7) * 8;   // read-side swizzled k-granule (elems)
    const int wvOff = wv * 512;                     // staging LDS offset (elems)
    const int aOff = (wM * 128 + lm) * 64;
    const int bOff = (wN * 48 + lm) * 64;

    // staging: chunk covers 64 panel rows; wave wv takes rows wv*8+(l>>3);
    // LDS pos p = l&7, fetch global granule p ^ ((r>>1)&7) = (l&7) ^ (4*(wv&1) + (l>>4)).
    const int gswz = ((lane & 7) ^ (4 * (wv & 1) + (lane >> 4))) & 7;
    const USHORT* aG[4];
    const USHORT* bG[3];
    #pragma unroll
    for (int j = 0; j < 4; ++j)
        aG[j] = A + (size_t)(m0 + j * 64 + wv * 8 + (lane >> 3)) * 4096 + gswz * 8;
    #pragma unroll
    for (int t = 0; t < 3; ++t)
        bG[t] = B + (size_t)(n0 + t * 64 + wv * 8 + (lane >> 3)) * 4096 + gswz * 8;

    f32x4 acc[8][3];
    #pragma unroll
    for (int a = 0; a < 8; ++a)
        #pragma unroll
        for (int b = 0; b < 3; ++b) {
            f32x4 z = {0.f, 0.f, 0.f, 0.f};
            acc[a][b] = z;
        }

    USHORT* aB0 = As;                    // tile t   (read)
    USHORT* aB1 = As + A_ELEMS;          // tile t+1 (in flight)
    USHORT* aB2 = As + 2 * A_ELEMS;      // tile t+2 (write)
    USHORT* bB0 = Bs;                    // tile t   parity
    USHORT* bB1 = Bs + B_ELEMS;

    // prologue: A(0), B(0), A(1), B(1) = 14 loads; vmcnt(7) -> A0,B0 landed.
    #pragma unroll
    for (int j = 0; j < 4; ++j) { load_lds16(aG[j], aB0 + j * 4096 + wvOff); aG[j] += 64; }
    #pragma unroll
    for (int t = 0; t < 3; ++t) { load_lds16(bG[t], bB0 + t * 4096 + wvOff); bG[t] += 64; }
    #pragma unroll
    for (int j = 0; j < 4; ++j) { load_lds16(aG[j], aB1 + j * 4096 + wvOff); aG[j] += 64; }
    #pragma unroll
    for (int t = 0; t < 3; ++t) { load_lds16(bG[t], bB1 + t * 4096 + wvOff); bG[t] += 64; }
    asm volatile("s_waitcnt vmcnt(7)" ::: "memory");
    __builtin_amdgcn_s_barrier();

    for (int kt = 0; kt < 62; ++kt) {
        do_tile<1, 0>(aB0 + aOff, bB0 + bOff, aB2 + wvOff, bB0 + wvOff,
                      aG, bG, koff0, acc);
        USHORT* tp = aB0; aB0 = aB1; aB1 = aB2; aB2 = tp;   // rotate A bufs
        tp = bB0; bB0 = bB1; bB1 = tp;                      // swap B bufs
    }
    do_tile<0, 1>(aB0 + aOff, bB0 + bOff, As, Bs, aG, bG, koff0, acc);  // kt=62: drain
    do_tile<0, 2>(aB1 + aOff, bB1 + bOff, As, Bs, aG, bG, koff0, acc);  // kt=63

    // epilogue: +bias, store bf16 gates. C/D: col = lane&15, row = (lane>>4)*4 + r.
    #pragma unroll
    for (int nt = 0; nt < 3; ++nt) {
        int gc = n0 + wN * 48 + nt * 16 + lm;
        float bb = (gc < 1024) ? bi[gc] : (gc < 2048 ? bfp[gc - 1024] : bc[gc - 2048]);
        #pragma unroll
        for (int mt = 0; mt < 8; ++mt) {
            #pragma unroll
            for (int r = 0; r < 4; ++r) {
                int lrow = wM * 128 + mt * 16 + (lane >> 4) * 4 + r;
                gates[(size_t)(m0 + lrow) * 3072 + gc] = f2bf(acc[mt][nt][r] + bb);
            }
        }
    }
}

// ---- elementwise epilogue: out = alpha*c + (1-alpha)*h
__global__ __launch_bounds__(256) void epi(const USHORT* __restrict__ gates,
                                           const float* __restrict__ h,
                                           float* __restrict__ out) {
    int e = (blockIdx.x * 256 + threadIdx.x) * 8;   // [0, 8192*1024)
    int m = e >> 10, n = e & 1023;
    const USHORT* gp = gates + (size_t)m * 3072 + n;
    union { USHORT us[8]; uint4 v; } gi, gf, gc;
    gi.v = *(const uint4*)(gp);
    gf.v = *(const uint4*)(gp + 1024);
    gc.v = *(const uint4*)(gp + 2048);
    const float* hp = h + (size_t)m * 1024 + n;
    float4 h0 = ((const float4*)hp)[0];
    float4 h1 = ((const float4*)hp)[1];
    float hv[8] = {h0.x, h0.y, h0.z, h0.w, h1.x, h1.y, h1.z, h1.w};
    float o[8];
    #pragma unroll
    for (int j = 0; j < 8; ++j) {
        float iv = sigm(bf2f(gi.us[j]));
        float fv = sigm(bf2f(gf.us[j]));
        float cv = mytanh(bf2f(gc.us[j]));
        float al = sigm(iv - fv);
        o[j] = al * cv + (1.f - al) * hv[j];
    }
    float4* op = (float4*)(out + (size_t)m * 1024 + n);
    op[0] = make_float4(o[0], o[1], o[2], o[3]);
    op[1] = make_float4(o[4], o[5], o[6], o[7]);
}

// ---- fallback: fused 3-phase kernel, register-convert staging (only if ws too small)
__global__ __launch_bounds__(256) void gemm3_noconv(const float* __restrict__ h,
                                                    const float* __restrict__ x,
                                                    const float* __restrict__ glo,
                                                    const float* __restrict__ Wi,
                                                    const float* __restrict__ Wf,
                                                    const float* __restrict__ Wc,
                                                    const float* __restrict__ bi,
                                                    const float* __restrict__ bfp,
                                                    const float* __restrict__ bc,
                                                    float* __restrict__ out) {
    __shared__ USHORT At[128 * 32];
    __shared__ USHORT Bt[128 * 32];
    __shared__ USHORT stash[128 * 136];

    const int tid  = threadIdx.x;
    const int lane = tid & 63, wv = tid >> 6;
    const int n0 = blockIdx.x * 128;
    const int m0 = blockIdx.y * 128;
    const int wM = wv >> 1, wN = wv & 1;
    const int lm = lane & 15, qk = (lane >> 4) * 8;
    const int rowS = tid >> 1;
    const int colS = (tid & 1) * 16;

    for (int p = 0; p < 3; ++p) {
        f32x4 acc[4][4];
        #pragma unroll
        for (int a = 0; a < 4; ++a)
            #pragma unroll
            for (int b = 0; b < 4; ++b) {
                f32x4 z = {0.f, 0.f, 0.f, 0.f};
                acc[a][b] = z;
            }
        const float* Wg = (p == 0) ? Wi : (p == 1 ? Wf : Wc);

        for (int kt = 0; kt < 128; ++kt) {
            __syncthreads();
            int k = kt * 32 + colS;
            const float* s;
            if (k < 1024)      s = h   + (size_t)(m0 + rowS) * 1024 + k;
            else if (k < 3072) s = x   + (size_t)(m0 + rowS) * 2048 + (k - 1024);
            else               s = glo + (size_t)(m0 + rowS) * 1024 + (k - 3072);
            float4 f0 = ((const float4*)s)[0], f1 = ((const float4*)s)[1];
            float4 f2 = ((const float4*)s)[2], f3 = ((const float4*)s)[3];
            union { USHORT us[8]; uint4 v; } u0, u1;
            u0.us[0]=f2bf(f0.x); u0.us[1]=f2bf(f0.y); u0.us[2]=f2bf(f0.z); u0.us[3]=f2bf(f0.w);
            u0.us[4]=f2bf(f1.x); u0.us[5]=f2bf(f1.y); u0.us[6]=f2bf(f1.z); u0.us[7]=f2bf(f1.w);
            u1.us[0]=f2bf(f2.x); u1.us[1]=f2bf(f2.y); u1.us[2]=f2bf(f2.z); u1.us[3]=f2bf(f2.w);
            u1.us[4]=f2bf(f3.x); u1.us[5]=f2bf(f3.y); u1.us[6]=f2bf(f3.z); u1.us[7]=f2bf(f3.w);
            *(uint4*)(At + rowS * 32 + colS)     = u0.v;
            *(uint4*)(At + rowS * 32 + colS + 8) = u1.v;
            const float* sw = Wg + (size_t)(n0 + rowS) * 4096 + k;
            float4 w0 = ((const float4*)sw)[0], w1 = ((const float4*)sw)[1];
            float4 w2 = ((const float4*)sw)[2], w3 = ((const float4*)sw)[3];
            union { USHORT us[8]; uint4 v; } v0, v1;
            v0.us[0]=f2bf(w0.x); v0.us[1]=f2bf(w0.y); v0.us[2]=f2bf(w0.z); v0.us[3]=f2bf(w0.w);
            v0.us[4]=f2bf(w1.x); v0.us[5]=f2bf(w1.y); v0.us[6]=f2bf(w1.z); v0.us[7]=f2bf(w1.w);
            v1.us[0]=f2bf(w2.x); v1.us[1]=f2bf(w2.y); v1.us[2]=f2bf(w2.z); v1.us[3]=f2bf(w2.w);
            v1.us[4]=f2bf(w3.x); v1.us[5]=f2bf(w3.y); v1.us[6]=f2bf(w3.z); v1.us[7]=f2bf(w3.w);
            *(uint4*)(Bt + rowS * 32 + colS)     = v0.v;
            *(uint4*)(Bt + rowS * 32 + colS + 8) = v1.v;
            __syncthreads();

            bf16x8 av[4], bv[4];
            #pragma unroll
            for (int mt = 0; mt < 4; ++mt)
                av[mt] = *(const bf16x8*)(At + (wM * 64 + mt * 16 + lm) * 32 + qk);
            #pragma unroll
            for (int nt = 0; nt < 4; ++nt)
                bv[nt] = *(const bf16x8*)(Bt + (wN * 64 + nt * 16 + lm) * 32 + qk);
            #pragma unroll
            for (int mt = 0; mt < 4; ++mt)
                #pragma unroll
                for (int nt = 0; nt < 4; ++nt)
                    acc[mt][nt] = __builtin_amdgcn_mfma_f32_16x16x32_bf16(
                        av[mt], bv[nt], acc[mt][nt], 0, 0, 0);
        }

        const float* bias = (p == 0) ? bi : (p == 1 ? bfp : bc);
        #pragma unroll
        for (int nt = 0; nt < 4; ++nt) {
            int lcol = wN * 64 + nt * 16 + lm;
            float bb = bias[n0 + lcol];
            #pragma unroll
            for (int mt = 0; mt < 4; ++mt) {
                #pragma unroll
                for (int r = 0; r < 4; ++r) {
                    int lrow = wM * 64 + mt * 16 + (lane >> 4) * 4 + r;
                    float g = acc[mt][nt][r] + bb;
                    int li = lrow * 136 + lcol;
                    if (p == 0) {
                        stash[li] = f2bf(sigm(g));
                    } else if (p == 1) {
                        float iv = bf2f(stash[li]);
                        stash[li] = f2bf(sigm(iv - sigm(g)));
                    } else {
                        float al = bf2f(stash[li]);
                        float cv = mytanh(g);
                        size_t gi = (size_t)(m0 + lrow) * 1024 + (n0 + lcol);
                        out[gi] = al * cv + (1.f - al) * h[gi];
                    }
                }
            }
        }
    }
}

extern "C" void kernel_launch(void* const* d_in, const int* in_sizes, int n_in,
                              void* d_out, int out_size, void* d_ws, size_t ws_size,
                              hipStream_t stream) {
    const float* h   = (const float*)d_in[0];
    const float* x   = (const float*)d_in[1];
    const float* glo = (const float*)d_in[2];
    const float* Wi  = (const float*)d_in[3];
    const float* bi  = (const float*)d_in[4];
    const float* Wf  = (const float*)d_in[5];
    const float* bfp = (const float*)d_in[6];
    const float* Wc  = (const float*)d_in[7];
    const float* bc  = (const float*)d_in[8];
    float* out = (float*)d_out;

    const size_t szA = (size_t)8192 * 4096 * 2;   // 64 MiB bf16 A
    const size_t szW = (size_t)3072 * 4096 * 2;   // 24 MiB bf16 W
    const size_t szG = (size_t)8192 * 3072 * 2;   // 48 MiB bf16 gates

    if (ws_size >= szA + szW + szG) {
        USHORT* Abf = (USHORT*)d_ws;
        USHORT* Wbf = (USHORT*)((char*)d_ws + szA);
        USHORT* Gbf = (USHORT*)((char*)d_ws + szA + szW);
        conv_all<<<16384 + 6144, 256, 0, stream>>>(h, x, glo, Wi, Wf, Wc, Abf, Wbf);
        gemm8p<<<512, 512, 0, stream>>>(Abf, Wbf, bi, bfp, bc, Gbf);
        epi<<<4096, 256, 0, stream>>>(Gbf, h, out);
    } else {
        gemm3_noconv<<<dim3(8, 64), 256, 0, stream>>>(
            h, x, glo, Wi, Wf, Wc, bi, bfp, bc, out);
    }
}

// Round 3
// 423.642 us; speedup vs baseline: 1.0886x; 1.0580x over previous
//
#include <hip/hip_runtime.h>

typedef unsigned short USHORT;
typedef short bf16x8 __attribute__((ext_vector_type(8)));
typedef float f32x4 __attribute__((ext_vector_type(4)));

__device__ __forceinline__ USHORT f2bf(float f) {
    unsigned u = __float_as_uint(f);
    u += 0x7fffu + ((u >> 16) & 1u);   // RNE, no NaNs in this problem
    return (USHORT)(u >> 16);
}
__device__ __forceinline__ float bf2f(USHORT s) {
    return __uint_as_float(((unsigned)s) << 16);
}
__device__ __forceinline__ float sigm(float v) { return 1.f / (1.f + __expf(-v)); }
__device__ __forceinline__ float mytanh(float v) { return 1.f - 2.f / (__expf(2.f * v) + 1.f); }

using gcu32p = const unsigned int __attribute__((address_space(1))) *;
using lu32p  = unsigned int __attribute__((address_space(3))) *;

__device__ __forceinline__ void load_lds16(const void* g, void* l) {
    __builtin_amdgcn_global_load_lds((gcu32p)g, (lu32p)l, 16, 0, 0);
}

// ---- single conversion kernel: fp32 sources -> bf16 A [8192x4096] and W [3072x4096]
__global__ __launch_bounds__(256) void conv_all(const float* __restrict__ h,
                                                const float* __restrict__ x,
                                                const float* __restrict__ glo,
                                                const float* __restrict__ Wi,
                                                const float* __restrict__ Wf,
                                                const float* __restrict__ Wc,
                                                USHORT* __restrict__ A,
                                                USHORT* __restrict__ W) {
    int bid = blockIdx.x;
    if (bid < 16384) {
        int idx = (bid * 256 + threadIdx.x) * 8;      // [0, 8192*4096)
        int m = idx >> 12, k = idx & 4095;
        const float* s;
        if (k < 1024)      s = h   + (size_t)m * 1024 + k;
        else if (k < 3072) s = x   + (size_t)m * 2048 + (k - 1024);
        else               s = glo + (size_t)m * 1024 + (k - 3072);
        float4 f0 = ((const float4*)s)[0];
        float4 f1 = ((const float4*)s)[1];
        union { USHORT us[8]; uint4 v; } u;
        u.us[0] = f2bf(f0.x); u.us[1] = f2bf(f0.y); u.us[2] = f2bf(f0.z); u.us[3] = f2bf(f0.w);
        u.us[4] = f2bf(f1.x); u.us[5] = f2bf(f1.y); u.us[6] = f2bf(f1.z); u.us[7] = f2bf(f1.w);
        *(uint4*)(A + idx) = u.v;
    } else {
        int idx = ((bid - 16384) * 256 + threadIdx.x) * 8;   // [0, 3072*4096)
        int n = idx >> 12, k = idx & 4095;
        const float* base = (n < 1024) ? Wi : (n < 2048 ? Wf : Wc);
        const float* s = base + (size_t)(n & 1023) * 4096 + k;
        float4 f0 = ((const float4*)s)[0];
        float4 f1 = ((const float4*)s)[1];
        union { USHORT us[8]; uint4 v; } u;
        u.us[0] = f2bf(f0.x); u.us[1] = f2bf(f0.y); u.us[2] = f2bf(f0.z); u.us[3] = f2bf(f0.w);
        u.us[4] = f2bf(f1.x); u.us[5] = f2bf(f1.y); u.us[6] = f2bf(f1.z); u.us[7] = f2bf(f1.w);
        *(uint4*)(W + idx) = u.v;
    }
}

// ============================================================================
// FUSED 8-phase GEMM + LSTM-gate epilogue:
//   out[8192,1024] = alpha*tanh(c) + (1-alpha)*h,  alpha = sigm(sigm(i)-sigm(f))
//   where [i|f|c](m,n) = A[m,:] . W[{0,1,2}*1024 + n, :] + bias
//
// Each block owns a 64-wide n-slice of H and computes ALL THREE gates for it:
//   B-chunk t (64 rows) stages W rows [t*1024 + n0, +64)  (t = gate index).
//   Wave layout 2M x 4N over (256 rows) x (64 n-cols): per-wave cols =
//   {gate g, n = wN*16+lm}  ->  the SAME lane holds i,f,c for identical
//   (row,n), so the gate epilogue is fully in-register; gates never hit HBM.
// GEMM core (unchanged from verified round-2 kernel): BM=256, 192 B-rows,
//   BK=64, 8 waves, deep pipeline (A triple-buf + B double-buf = 144 KiB,
//   2-tile prefetch, single end-of-tile vmcnt(7)), granule XOR swizzle both
//   sides (bank-conflict counter = 0). Only bOff / bv stride / bG bases and
//   the epilogue changed.
// Grid 512 = 32 m-blocks x 16 n-slices, XCD-swizzled (per XCD: 2 n-slices,
//   3 MB of W -> L2-resident).
// ============================================================================

#define A_ELEMS 16384   // 256*64 per buffer
#define B_ELEMS 12288   // 192*64 per buffer

template<int ISS, int WMODE>   // WMODE 0: vmcnt(7), 1: vmcnt(0), 2: none
__device__ __forceinline__ void do_tile(const USHORT* aRd, const USHORT* bRd,
                                        USHORT* aWr, USHORT* bWr,
                                        const USHORT* (&aG)[4], const USHORT* (&bG)[3],
                                        int koff0, f32x4 (&acc)[8][3]) {
    bf16x8 bv[3][2];
    #pragma unroll
    for (int q = 0; q < 4; ++q) {
        bf16x8 av[2][2];
        #pragma unroll
        for (int m2 = 0; m2 < 2; ++m2)
            #pragma unroll
            for (int kh = 0; kh < 2; ++kh)
                av[m2][kh] = *(const bf16x8*)(aRd + (q * 32 + m2 * 16) * 64 + (koff0 ^ (kh * 32)));
        if (q == 0) {
            #pragma unroll
            for (int nt = 0; nt < 3; ++nt)        // nt = gate; B rows 64 apart
                #pragma unroll
                for (int kh = 0; kh < 2; ++kh)
                    bv[nt][kh] = *(const bf16x8*)(bRd + nt * 4096 + (koff0 ^ (kh * 32)));
        }
        if (ISS) {
            if (q == 0) {            // stage A(t+2) into rotation buffer
                load_lds16(aG[0], aWr);
                load_lds16(aG[1], aWr + 4096);
                aG[0] += 64; aG[1] += 64;
            } else if (q == 1) {
                load_lds16(aG[2], aWr + 8192);
                load_lds16(aG[3], aWr + 12288);
                aG[2] += 64; aG[3] += 64;
            } else if (q == 2) {     // stage B(t+2) into same-parity buffer
                load_lds16(bG[0], bWr);
                load_lds16(bG[1], bWr + 4096);
                bG[0] += 64; bG[1] += 64;
            } else {
                load_lds16(bG[2], bWr + 8192);
                bG[2] += 64;
            }
        }
        __builtin_amdgcn_sched_barrier(0);
        __builtin_amdgcn_s_barrier();
        __builtin_amdgcn_s_setprio(1);
        #pragma unroll
        for (int m2 = 0; m2 < 2; ++m2)
            #pragma unroll
            for (int nt = 0; nt < 3; ++nt)
                #pragma unroll
                for (int kh = 0; kh < 2; ++kh)
                    acc[q * 2 + m2][nt] = __builtin_amdgcn_mfma_f32_16x16x32_bf16(
                        av[m2][kh], bv[nt][kh], acc[q * 2 + m2][nt], 0, 0, 0);
        __builtin_amdgcn_s_setprio(0);
        if (q == 3) {
            if (WMODE == 0) asm volatile("s_waitcnt vmcnt(7)" ::: "memory");
            else if (WMODE == 1) asm volatile("s_waitcnt vmcnt(0)" ::: "memory");
        }
        __builtin_amdgcn_s_barrier();
    }
}

__global__ __launch_bounds__(512, 2) void gemm_fused(const USHORT* __restrict__ A,
                                                     const USHORT* __restrict__ B,
                                                     const float* __restrict__ bi,
                                                     const float* __restrict__ bfp,
                                                     const float* __restrict__ bc,
                                                     const float* __restrict__ h,
                                                     float* __restrict__ out) {
    __shared__ __align__(16) USHORT As[3 * 256 * 64];   // 96 KiB (triple buffer)
    __shared__ __align__(16) USHORT Bs[2 * 192 * 64];   // 48 KiB (double buffer)

    const int tid  = threadIdx.x;
    const int lane = tid & 63, wv = tid >> 6;
    // XCD-aware bijective swizzle (512 % 8 == 0).
    const int s  = (blockIdx.x & 7) * 64 + (blockIdx.x >> 3);
    const int m0 = (s & 31) * 256;
    const int n0 = (s >> 5) * 64;           // n-slice of H (16 slices)

    const int wM = wv >> 2, wN = wv & 3;    // 2 x 4 wave grid
    const int lm = lane & 15;
    const int gw = lane >> 4;
    const int koff0 = ((gw ^ (lm >> 1)) & 7) * 8;   // read-side swizzled k-granule (elems)
    const int wvOff = wv * 512;                     // staging LDS offset (elems)
    const int aOff = (wM * 128 + lm) * 64;
    const int bOff = (wN * 16 + lm) * 64;           // n within 64-slice; gates at +nt*4096

    // staging: chunk covers 64 panel rows; wave wv takes rows wv*8+(l>>3);
    // LDS pos p = l&7, fetch global granule p ^ ((r>>1)&7) = (l&7) ^ (4*(wv&1) + (l>>4)).
    const int gswz = ((lane & 7) ^ (4 * (wv & 1) + (lane >> 4))) & 7;
    const USHORT* aG[4];
    const USHORT* bG[3];
    #pragma unroll
    for (int j = 0; j < 4; ++j)
        aG[j] = A + (size_t)(m0 + j * 64 + wv * 8 + (lane >> 3)) * 4096 + gswz * 8;
    #pragma unroll
    for (int t = 0; t < 3; ++t)   // chunk t = gate t: W rows t*1024 + n0 ...
        bG[t] = B + (size_t)(t * 1024 + n0 + wv * 8 + (lane >> 3)) * 4096 + gswz * 8;

    f32x4 acc[8][3];
    #pragma unroll
    for (int a = 0; a < 8; ++a)
        #pragma unroll
        for (int b = 0; b < 3; ++b) {
            f32x4 z = {0.f, 0.f, 0.f, 0.f};
            acc[a][b] = z;
        }

    USHORT* aB0 = As;                    // tile t   (read)
    USHORT* aB1 = As + A_ELEMS;          // tile t+1 (in flight)
    USHORT* aB2 = As + 2 * A_ELEMS;      // tile t+2 (write)
    USHORT* bB0 = Bs;                    // tile t   parity
    USHORT* bB1 = Bs + B_ELEMS;

    // prologue: A(0), B(0), A(1), B(1) = 14 loads; vmcnt(7) -> A0,B0 landed.
    #pragma unroll
    for (int j = 0; j < 4; ++j) { load_lds16(aG[j], aB0 + j * 4096 + wvOff); aG[j] += 64; }
    #pragma unroll
    for (int t = 0; t < 3; ++t) { load_lds16(bG[t], bB0 + t * 4096 + wvOff); bG[t] += 64; }
    #pragma unroll
    for (int j = 0; j < 4; ++j) { load_lds16(aG[j], aB1 + j * 4096 + wvOff); aG[j] += 64; }
    #pragma unroll
    for (int t = 0; t < 3; ++t) { load_lds16(bG[t], bB1 + t * 4096 + wvOff); bG[t] += 64; }
    asm volatile("s_waitcnt vmcnt(7)" ::: "memory");
    __builtin_amdgcn_s_barrier();

    for (int kt = 0; kt < 62; ++kt) {
        do_tile<1, 0>(aB0 + aOff, bB0 + bOff, aB2 + wvOff, bB0 + wvOff,
                      aG, bG, koff0, acc);
        USHORT* tp = aB0; aB0 = aB1; aB1 = aB2; aB2 = tp;   // rotate A bufs
        tp = bB0; bB0 = bB1; bB1 = tp;                      // swap B bufs
    }
    do_tile<0, 1>(aB0 + aOff, bB0 + bOff, As, Bs, aG, bG, koff0, acc);  // kt=62: drain
    do_tile<0, 2>(aB1 + aOff, bB1 + bOff, As, Bs, aG, bG, koff0, acc);  // kt=63

    // fused epilogue: same lane holds i (nt=0), f (nt=1), c (nt=2) for one
    // (row, n). C/D layout: col = lane&15 (the n within the 16-stripe),
    // row = (lane>>4)*4 + r.
    const int nc = n0 + wN * 16 + lm;
    const float bbi = bi[nc], bbf = bfp[nc], bbc = bc[nc];
    #pragma unroll
    for (int mt = 0; mt < 8; ++mt) {
        #pragma unroll
        for (int r = 0; r < 4; ++r) {
            int lrow = wM * 128 + mt * 16 + (lane >> 4) * 4 + r;
            size_t off = (size_t)(m0 + lrow) * 1024 + nc;
            float gi_ = acc[mt][0][r] + bbi;
            float gf_ = acc[mt][1][r] + bbf;
            float gc_ = acc[mt][2][r] + bbc;
            float iv = sigm(gi_);
            float fv = sigm(gf_);
            float al = sigm(iv - fv);
            float cv = mytanh(gc_);
            out[off] = al * cv + (1.f - al) * h[off];
        }
    }
}

// ---- fallback: fused 3-phase kernel, register-convert staging (only if ws too small)
__global__ __launch_bounds__(256) void gemm3_noconv(const float* __restrict__ h,
                                                    const float* __restrict__ x,
                                                    const float* __restrict__ glo,
                                                    const float* __restrict__ Wi,
                                                    const float* __restrict__ Wf,
                                                    const float* __restrict__ Wc,
                                                    const float* __restrict__ bi,
                                                    const float* __restrict__ bfp,
                                                    const float* __restrict__ bc,
                                                    float* __restrict__ out) {
    __shared__ USHORT At[128 * 32];
    __shared__ USHORT Bt[128 * 32];
    __shared__ USHORT stash[128 * 136];

    const int tid  = threadIdx.x;
    const int lane = tid & 63, wv = tid >> 6;
    const int n0 = blockIdx.x * 128;
    const int m0 = blockIdx.y * 128;
    const int wM = wv >> 1, wN = wv & 1;
    const int lm = lane & 15, qk = (lane >> 4) * 8;
    const int rowS = tid >> 1;
    const int colS = (tid & 1) * 16;

    for (int p = 0; p < 3; ++p) {
        f32x4 acc[4][4];
        #pragma unroll
        for (int a = 0; a < 4; ++a)
            #pragma unroll
            for (int b = 0; b < 4; ++b) {
                f32x4 z = {0.f, 0.f, 0.f, 0.f};
                acc[a][b] = z;
            }
        const float* Wg = (p == 0) ? Wi : (p == 1 ? Wf : Wc);

        for (int kt = 0; kt < 128; ++kt) {
            __syncthreads();
            int k = kt * 32 + colS;
            const float* s;
            if (k < 1024)      s = h   + (size_t)(m0 + rowS) * 1024 + k;
            else if (k < 3072) s = x   + (size_t)(m0 + rowS) * 2048 + (k - 1024);
            else               s = glo + (size_t)(m0 + rowS) * 1024 + (k - 3072);
            float4 f0 = ((const float4*)s)[0], f1 = ((const float4*)s)[1];
            float4 f2 = ((const float4*)s)[2], f3 = ((const float4*)s)[3];
            union { USHORT us[8]; uint4 v; } u0, u1;
            u0.us[0]=f2bf(f0.x); u0.us[1]=f2bf(f0.y); u0.us[2]=f2bf(f0.z); u0.us[3]=f2bf(f0.w);
            u0.us[4]=f2bf(f1.x); u0.us[5]=f2bf(f1.y); u0.us[6]=f2bf(f1.z); u0.us[7]=f2bf(f1.w);
            u1.us[0]=f2bf(f2.x); u1.us[1]=f2bf(f2.y); u1.us[2]=f2bf(f2.z); u1.us[3]=f2bf(f2.w);
            u1.us[4]=f2bf(f3.x); u1.us[5]=f2bf(f3.y); u1.us[6]=f2bf(f3.z); u1.us[7]=f2bf(f3.w);
            *(uint4*)(At + rowS * 32 + colS)     = u0.v;
            *(uint4*)(At + rowS * 32 + colS + 8) = u1.v;
            const float* sw = Wg + (size_t)(n0 + rowS) * 4096 + k;
            float4 w0 = ((const float4*)sw)[0], w1 = ((const float4*)sw)[1];
            float4 w2 = ((const float4*)sw)[2], w3 = ((const float4*)sw)[3];
            union { USHORT us[8]; uint4 v; } v0, v1;
            v0.us[0]=f2bf(w0.x); v0.us[1]=f2bf(w0.y); v0.us[2]=f2bf(w0.z); v0.us[3]=f2bf(w0.w);
            v0.us[4]=f2bf(w1.x); v0.us[5]=f2bf(w1.y); v0.us[6]=f2bf(w1.z); v0.us[7]=f2bf(w1.w);
            v1.us[0]=f2bf(w2.x); v1.us[1]=f2bf(w2.y); v1.us[2]=f2bf(w2.z); v1.us[3]=f2bf(w2.w);
            v1.us[4]=f2bf(w3.x); v1.us[5]=f2bf(w3.y); v1.us[6]=f2bf(w3.z); v1.us[7]=f2bf(w3.w);
            *(uint4*)(Bt + rowS * 32 + colS)     = v0.v;
            *(uint4*)(Bt + rowS * 32 + colS + 8) = v1.v;
            __syncthreads();

            bf16x8 av[4], bv[4];
            #pragma unroll
            for (int mt = 0; mt < 4; ++mt)
                av[mt] = *(const bf16x8*)(At + (wM * 64 + mt * 16 + lm) * 32 + qk);
            #pragma unroll
            for (int nt = 0; nt < 4; ++nt)
                bv[nt] = *(const bf16x8*)(Bt + (wN * 64 + nt * 16 + lm) * 32 + qk);
            #pragma unroll
            for (int mt = 0; mt < 4; ++mt)
                #pragma unroll
                for (int nt = 0; nt < 4; ++nt)
                    acc[mt][nt] = __builtin_amdgcn_mfma_f32_16x16x32_bf16(
                        av[mt], bv[nt], acc[mt][nt], 0, 0, 0);
        }

        const float* bias = (p == 0) ? bi : (p == 1 ? bfp : bc);
        #pragma unroll
        for (int nt = 0; nt < 4; ++nt) {
            int lcol = wN * 64 + nt * 16 + lm;
            float bb = bias[n0 + lcol];
            #pragma unroll
            for (int mt = 0; mt < 4; ++mt) {
                #pragma unroll
                for (int r = 0; r < 4; ++r) {
                    int lrow = wM * 64 + mt * 16 + (lane >> 4) * 4 + r;
                    float g = acc[mt][nt][r] + bb;
                    int li = lrow * 136 + lcol;
                    if (p == 0) {
                        stash[li] = f2bf(sigm(g));
                    } else if (p == 1) {
                        float iv = bf2f(stash[li]);
                        stash[li] = f2bf(sigm(iv - sigm(g)));
                    } else {
                        float al = bf2f(stash[li]);
                        float cv = mytanh(g);
                        size_t gi = (size_t)(m0 + lrow) * 1024 + (n0 + lcol);
                        out[gi] = al * cv + (1.f - al) * h[gi];
                    }
                }
            }
        }
    }
}

extern "C" void kernel_launch(void* const* d_in, const int* in_sizes, int n_in,
                              void* d_out, int out_size, void* d_ws, size_t ws_size,
                              hipStream_t stream) {
    const float* h   = (const float*)d_in[0];
    const float* x   = (const float*)d_in[1];
    const float* glo = (const float*)d_in[2];
    const float* Wi  = (const float*)d_in[3];
    const float* bi  = (const float*)d_in[4];
    const float* Wf  = (const float*)d_in[5];
    const float* bfp = (const float*)d_in[6];
    const float* Wc  = (const float*)d_in[7];
    const float* bc  = (const float*)d_in[8];
    float* out = (float*)d_out;

    const size_t szA = (size_t)8192 * 4096 * 2;   // 64 MiB bf16 A
    const size_t szW = (size_t)3072 * 4096 * 2;   // 24 MiB bf16 W

    if (ws_size >= szA + szW) {
        USHORT* Abf = (USHORT*)d_ws;
        USHORT* Wbf = (USHORT*)((char*)d_ws + szA);
        conv_all<<<16384 + 6144, 256, 0, stream>>>(h, x, glo, Wi, Wf, Wc, Abf, Wbf);
        gemm_fused<<<512, 512, 0, stream>>>(Abf, Wbf, bi, bfp, bc, h, out);
    } else {
        gemm3_noconv<<<dim3(8, 64), 256, 0, stream>>>(
            h, x, glo, Wi, Wf, Wc, bi, bfp, bc, out);
    }
}

// Round 4
// 394.343 us; speedup vs baseline: 1.1694x; 1.0743x over previous
//
#include <hip/hip_runtime.h>

typedef unsigned short USHORT;
typedef short bf16x8 __attribute__((ext_vector_type(8)));
typedef float f32x4 __attribute__((ext_vector_type(4)));

__device__ __forceinline__ USHORT f2bf(float f) {
    unsigned u = __float_as_uint(f);
    u += 0x7fffu + ((u >> 16) & 1u);   // RNE, no NaNs in this problem
    return (USHORT)(u >> 16);
}
__device__ __forceinline__ float bf2f(USHORT s) {
    return __uint_as_float(((unsigned)s) << 16);
}
__device__ __forceinline__ float sigm(float v) { return 1.f / (1.f + __expf(-v)); }
__device__ __forceinline__ float mytanh(float v) { return 1.f - 2.f / (__expf(2.f * v) + 1.f); }

using gcu32p = const unsigned int __attribute__((address_space(1))) *;
using lu32p  = unsigned int __attribute__((address_space(3))) *;
using lusp   = const USHORT __attribute__((address_space(3))) *;

__device__ __forceinline__ void load_lds16(const void* g, void* l) {
    __builtin_amdgcn_global_load_lds((gcu32p)g, (lu32p)l, 16, 0, 0);
}

// Inline-asm ds_read_b128: NO memory operand -> the compiler cannot insert a
// conservative s_waitcnt vmcnt() before it to order it against outstanding
// global_load_lds DMA (the hypothesized serializer of the 8-phase pipeline).
// Data-readiness is guaranteed by OUR explicit vmcnt(7)+barrier schedule.
__device__ __forceinline__ bf16x8 ds_read16(const USHORT* p) {
    bf16x8 r;
    unsigned a = (unsigned)(unsigned long long)(lusp)p;   // generic -> LDS offset
    asm volatile("ds_read_b128 %0, %1" : "=v"(r) : "v"(a));
    return r;
}

// ---- conversion kernel: fp32 sources -> bf16 A [8192x4096] and W [3072x4096]
// 16 elems/thread (4 in-flight float4 loads, 2 uint4 stores).
__global__ __launch_bounds__(256) void conv_all(const float* __restrict__ h,
                                                const float* __restrict__ x,
                                                const float* __restrict__ glo,
                                                const float* __restrict__ Wi,
                                                const float* __restrict__ Wf,
                                                const float* __restrict__ Wc,
                                                USHORT* __restrict__ A,
                                                USHORT* __restrict__ W) {
    int bid = blockIdx.x;
    const float* s;
    USHORT* dst;
    int idx;
    if (bid < 8192) {
        idx = (bid * 256 + threadIdx.x) * 16;      // [0, 8192*4096)
        int m = idx >> 12, k = idx & 4095;         // region boundaries %16==0
        if (k < 1024)      s = h   + (size_t)m * 1024 + k;
        else if (k < 3072) s = x   + (size_t)m * 2048 + (k - 1024);
        else               s = glo + (size_t)m * 1024 + (k - 3072);
        dst = A + idx;
    } else {
        idx = ((bid - 8192) * 256 + threadIdx.x) * 16;   // [0, 3072*4096)
        int n = idx >> 12, k = idx & 4095;
        const float* base = (n < 1024) ? Wi : (n < 2048 ? Wf : Wc);
        s = base + (size_t)(n & 1023) * 4096 + k;
        dst = W + idx;
    }
    float4 f0 = ((const float4*)s)[0];
    float4 f1 = ((const float4*)s)[1];
    float4 f2 = ((const float4*)s)[2];
    float4 f3 = ((const float4*)s)[3];
    union { USHORT us[16]; uint4 v[2]; } u;
    u.us[0]  = f2bf(f0.x); u.us[1]  = f2bf(f0.y); u.us[2]  = f2bf(f0.z); u.us[3]  = f2bf(f0.w);
    u.us[4]  = f2bf(f1.x); u.us[5]  = f2bf(f1.y); u.us[6]  = f2bf(f1.z); u.us[7]  = f2bf(f1.w);
    u.us[8]  = f2bf(f2.x); u.us[9]  = f2bf(f2.y); u.us[10] = f2bf(f2.z); u.us[11] = f2bf(f2.w);
    u.us[12] = f2bf(f3.x); u.us[13] = f2bf(f3.y); u.us[14] = f2bf(f3.z); u.us[15] = f2bf(f3.w);
    ((uint4*)dst)[0] = u.v[0];
    ((uint4*)dst)[1] = u.v[1];
}

// ============================================================================
// FUSED 8-phase GEMM + LSTM-gate epilogue (schedule identical to verified
// round-3 kernel; ONLY the LDS fragment reads changed to inline-asm ds_read
// with explicit lgkmcnt(0) + sched_barrier(0) per rule #18, so the counted
// vmcnt(7) pipeline actually survives compilation).
//
// BM=256, 192 B-rows (3 gates x 64 n), BK=64, 8 waves (2M x 4N).
// LDS: A triple-buffer (3x32K) + B double-buffer (2x24K) = 144 KiB.
// Tile t, 4 phases: {asm ds_reads | issue staging -> SB -> s_barrier ->
//   lgkmcnt(0) -> SB -> setprio(1) -> 12 MFMA -> setprio(0) -> SB ->
//   [q3: vmcnt(7)] -> s_barrier}.  p0/p1 stage A(t+2), p2/p3 stage B(t+2).
// End-of-tile queue = [A(t+1)x4, B(t+1)x3, A(t+2)x4, B(t+2)x3]; vmcnt(7)
//   retires exactly through B(t+1).  Tails: t=62 vmcnt(0), t=63 none.
// Granule XOR swizzle both sides (bank-conflict counter == 0, verified).
// ============================================================================

#define A_ELEMS 16384   // 256*64 per buffer
#define B_ELEMS 12288   // 192*64 per buffer

template<int ISS, int WMODE>   // WMODE 0: vmcnt(7), 1: vmcnt(0), 2: none
__device__ __forceinline__ void do_tile(const USHORT* aRd, const USHORT* bRd,
                                        USHORT* aWr, USHORT* bWr,
                                        const USHORT* (&aG)[4], const USHORT* (&bG)[3],
                                        int koff0, f32x4 (&acc)[8][3]) {
    bf16x8 bv[3][2];
    #pragma unroll
    for (int q = 0; q < 4; ++q) {
        __builtin_amdgcn_sched_barrier(0);
        bf16x8 av[2][2];
        #pragma unroll
        for (int m2 = 0; m2 < 2; ++m2)
            #pragma unroll
            for (int kh = 0; kh < 2; ++kh)
                av[m2][kh] = ds_read16(aRd + (q * 32 + m2 * 16) * 64 + (koff0 ^ (kh * 32)));
        if (q == 0) {
            #pragma unroll
            for (int nt = 0; nt < 3; ++nt)        // nt = gate; B rows 64 apart
                #pragma unroll
                for (int kh = 0; kh < 2; ++kh)
                    bv[nt][kh] = ds_read16(bRd + nt * 4096 + (koff0 ^ (kh * 32)));
        }
        if (ISS) {
            if (q == 0) {            // stage A(t+2) into rotation buffer
                load_lds16(aG[0], aWr);
                load_lds16(aG[1], aWr + 4096);
                aG[0] += 64; aG[1] += 64;
            } else if (q == 1) {
                load_lds16(aG[2], aWr + 8192);
                load_lds16(aG[3], aWr + 12288);
                aG[2] += 64; aG[3] += 64;
            } else if (q == 2) {     // stage B(t+2) into same-parity buffer
                load_lds16(bG[0], bWr);
                load_lds16(bG[1], bWr + 4096);
                bG[0] += 64; bG[1] += 64;
            } else {
                load_lds16(bG[2], bWr + 8192);
                bG[2] += 64;
            }
        }
        __builtin_amdgcn_sched_barrier(0);
        __builtin_amdgcn_s_barrier();
        asm volatile("s_waitcnt lgkmcnt(0)");
        __builtin_amdgcn_sched_barrier(0);       // rule #18: pin MFMA after wait
        __builtin_amdgcn_s_setprio(1);
        #pragma unroll
        for (int m2 = 0; m2 < 2; ++m2)
            #pragma unroll
            for (int nt = 0; nt < 3; ++nt)
                #pragma unroll
                for (int kh = 0; kh < 2; ++kh)
                    acc[q * 2 + m2][nt] = __builtin_amdgcn_mfma_f32_16x16x32_bf16(
                        av[m2][kh], bv[nt][kh], acc[q * 2 + m2][nt], 0, 0, 0);
        __builtin_amdgcn_s_setprio(0);
        __builtin_amdgcn_sched_barrier(0);
        if (q == 3) {
            if (WMODE == 0) asm volatile("s_waitcnt vmcnt(7)" ::: "memory");
            else if (WMODE == 1) asm volatile("s_waitcnt vmcnt(0)" ::: "memory");
        }
        __builtin_amdgcn_s_barrier();
    }
}

__global__ __launch_bounds__(512, 2) void gemm_fused(const USHORT* __restrict__ A,
                                                     const USHORT* __restrict__ B,
                                                     const float* __restrict__ bi,
                                                     const float* __restrict__ bfp,
                                                     const float* __restrict__ bc,
                                                     const float* __restrict__ h,
                                                     float* __restrict__ out) {
    __shared__ __align__(16) USHORT As[3 * 256 * 64];   // 96 KiB (triple buffer)
    __shared__ __align__(16) USHORT Bs[2 * 192 * 64];   // 48 KiB (double buffer)

    const int tid  = threadIdx.x;
    const int lane = tid & 63, wv = tid >> 6;
    // XCD-aware bijective swizzle (512 % 8 == 0).
    const int s  = (blockIdx.x & 7) * 64 + (blockIdx.x >> 3);
    const int m0 = (s & 31) * 256;
    const int n0 = (s >> 5) * 64;           // n-slice of H (16 slices)

    const int wM = wv >> 2, wN = wv & 3;    // 2 x 4 wave grid
    const int lm = lane & 15;
    const int gw = lane >> 4;
    const int koff0 = ((gw ^ (lm >> 1)) & 7) * 8;   // read-side swizzled k-granule (elems)
    const int wvOff = wv * 512;                     // staging LDS offset (elems)
    const int aOff = (wM * 128 + lm) * 64;
    const int bOff = (wN * 16 + lm) * 64;           // n within 64-slice; gates at +nt*4096

    // staging: chunk covers 64 panel rows; wave wv takes rows wv*8+(l>>3);
    // LDS pos p = l&7, fetch global granule p ^ ((r>>1)&7) = (l&7) ^ (4*(wv&1) + (l>>4)).
    const int gswz = ((lane & 7) ^ (4 * (wv & 1) + (lane >> 4))) & 7;
    const USHORT* aG[4];
    const USHORT* bG[3];
    #pragma unroll
    for (int j = 0; j < 4; ++j)
        aG[j] = A + (size_t)(m0 + j * 64 + wv * 8 + (lane >> 3)) * 4096 + gswz * 8;
    #pragma unroll
    for (int t = 0; t < 3; ++t)   // chunk t = gate t: W rows t*1024 + n0 ...
        bG[t] = B + (size_t)(t * 1024 + n0 + wv * 8 + (lane >> 3)) * 4096 + gswz * 8;

    f32x4 acc[8][3];
    #pragma unroll
    for (int a = 0; a < 8; ++a)
        #pragma unroll
        for (int b = 0; b < 3; ++b) {
            f32x4 z = {0.f, 0.f, 0.f, 0.f};
            acc[a][b] = z;
        }

    USHORT* aB0 = As;                    // tile t   (read)
    USHORT* aB1 = As + A_ELEMS;          // tile t+1 (in flight)
    USHORT* aB2 = As + 2 * A_ELEMS;      // tile t+2 (write)
    USHORT* bB0 = Bs;                    // tile t   parity
    USHORT* bB1 = Bs + B_ELEMS;

    // prologue: A(0), B(0), A(1), B(1) = 14 loads; vmcnt(7) -> A0,B0 landed.
    #pragma unroll
    for (int j = 0; j < 4; ++j) { load_lds16(aG[j], aB0 + j * 4096 + wvOff); aG[j] += 64; }
    #pragma unroll
    for (int t = 0; t < 3; ++t) { load_lds16(bG[t], bB0 + t * 4096 + wvOff); bG[t] += 64; }
    #pragma unroll
    for (int j = 0; j < 4; ++j) { load_lds16(aG[j], aB1 + j * 4096 + wvOff); aG[j] += 64; }
    #pragma unroll
    for (int t = 0; t < 3; ++t) { load_lds16(bG[t], bB1 + t * 4096 + wvOff); bG[t] += 64; }
    asm volatile("s_waitcnt vmcnt(7)" ::: "memory");
    __builtin_amdgcn_s_barrier();

    for (int kt = 0; kt < 62; ++kt) {
        do_tile<1, 0>(aB0 + aOff, bB0 + bOff, aB2 + wvOff, bB0 + wvOff,
                      aG, bG, koff0, acc);
        USHORT* tp = aB0; aB0 = aB1; aB1 = aB2; aB2 = tp;   // rotate A bufs
        tp = bB0; bB0 = bB1; bB1 = tp;                      // swap B bufs
    }
    do_tile<0, 1>(aB0 + aOff, bB0 + bOff, As, Bs, aG, bG, koff0, acc);  // kt=62: drain
    do_tile<0, 2>(aB1 + aOff, bB1 + bOff, As, Bs, aG, bG, koff0, acc);  // kt=63

    // fused epilogue: same lane holds i (nt=0), f (nt=1), c (nt=2) for one
    // (row, n). C/D layout: col = lane&15, row = (lane>>4)*4 + r.
    const int nc = n0 + wN * 16 + lm;
    const float bbi = bi[nc], bbf = bfp[nc], bbc = bc[nc];
    #pragma unroll
    for (int mt = 0; mt < 8; ++mt) {
        #pragma unroll
        for (int r = 0; r < 4; ++r) {
            int lrow = wM * 128 + mt * 16 + (lane >> 4) * 4 + r;
            size_t off = (size_t)(m0 + lrow) * 1024 + nc;
            float gi_ = acc[mt][0][r] + bbi;
            float gf_ = acc[mt][1][r] + bbf;
            float gc_ = acc[mt][2][r] + bbc;
            float iv = sigm(gi_);
            float fv = sigm(gf_);
            float al = sigm(iv - fv);
            float cv = mytanh(gc_);
            out[off] = al * cv + (1.f - al) * h[off];
        }
    }
}

// ---- fallback: fused 3-phase kernel, register-convert staging (only if ws too small)
__global__ __launch_bounds__(256) void gemm3_noconv(const float* __restrict__ h,
                                                    const float* __restrict__ x,
                                                    const float* __restrict__ glo,
                                                    const float* __restrict__ Wi,
                                                    const float* __restrict__ Wf,
                                                    const float* __restrict__ Wc,
                                                    const float* __restrict__ bi,
                                                    const float* __restrict__ bfp,
                                                    const float* __restrict__ bc,
                                                    float* __restrict__ out) {
    __shared__ USHORT At[128 * 32];
    __shared__ USHORT Bt[128 * 32];
    __shared__ USHORT stash[128 * 136];

    const int tid  = threadIdx.x;
    const int lane = tid & 63, wv = tid >> 6;
    const int n0 = blockIdx.x * 128;
    const int m0 = blockIdx.y * 128;
    const int wM = wv >> 1, wN = wv & 1;
    const int lm = lane & 15, qk = (lane >> 4) * 8;
    const int rowS = tid >> 1;
    const int colS = (tid & 1) * 16;

    for (int p = 0; p < 3; ++p) {
        f32x4 acc[4][4];
        #pragma unroll
        for (int a = 0; a < 4; ++a)
            #pragma unroll
            for (int b = 0; b < 4; ++b) {
                f32x4 z = {0.f, 0.f, 0.f, 0.f};
                acc[a][b] = z;
            }
        const float* Wg = (p == 0) ? Wi : (p == 1 ? Wf : Wc);

        for (int kt = 0; kt < 128; ++kt) {
            __syncthreads();
            int k = kt * 32 + colS;
            const float* s;
            if (k < 1024)      s = h   + (size_t)(m0 + rowS) * 1024 + k;
            else if (k < 3072) s = x   + (size_t)(m0 + rowS) * 2048 + (k - 1024);
            else               s = glo + (size_t)(m0 + rowS) * 1024 + (k - 3072);
            float4 f0 = ((const float4*)s)[0], f1 = ((const float4*)s)[1];
            float4 f2 = ((const float4*)s)[2], f3 = ((const float4*)s)[3];
            union { USHORT us[8]; uint4 v; } u0, u1;
            u0.us[0]=f2bf(f0.x); u0.us[1]=f2bf(f0.y); u0.us[2]=f2bf(f0.z); u0.us[3]=f2bf(f0.w);
            u0.us[4]=f2bf(f1.x); u0.us[5]=f2bf(f1.y); u0.us[6]=f2bf(f1.z); u0.us[7]=f2bf(f1.w);
            u1.us[0]=f2bf(f2.x); u1.us[1]=f2bf(f2.y); u1.us[2]=f2bf(f2.z); u1.us[3]=f2bf(f2.w);
            u1.us[4]=f2bf(f3.x); u1.us[5]=f2bf(f3.y); u1.us[6]=f2bf(f3.z); u1.us[7]=f2bf(f3.w);
            *(uint4*)(At + rowS * 32 + colS)     = u0.v;
            *(uint4*)(At + rowS * 32 + colS + 8) = u1.v;
            const float* sw = Wg + (size_t)(n0 + rowS) * 4096 + k;
            float4 w0 = ((const float4*)sw)[0], w1 = ((const float4*)sw)[1];
            float4 w2 = ((const float4*)sw)[2], w3 = ((const float4*)sw)[3];
            union { USHORT us[8]; uint4 v; } v0, v1;
            v0.us[0]=f2bf(w0.x); v0.us[1]=f2bf(w0.y); v0.us[2]=f2bf(w0.z); v0.us[3]=f2bf(w0.w);
            v0.us[4]=f2bf(w1.x); v0.us[5]=f2bf(w1.y); v0.us[6]=f2bf(w1.z); v0.us[7]=f2bf(w1.w);
            v1.us[0]=f2bf(w2.x); v1.us[1]=f2bf(w2.y); v1.us[2]=f2bf(w2.z); v1.us[3]=f2bf(w2.w);
            v1.us[4]=f2bf(w3.x); v1.us[5]=f2bf(w3.y); v1.us[6]=f2bf(w3.z); v1.us[7]=f2bf(w3.w);
            *(uint4*)(Bt + rowS * 32 + colS)     = v0.v;
            *(uint4*)(Bt + rowS * 32 + colS + 8) = v1.v;
            __syncthreads();

            bf16x8 av[4], bv[4];
            #pragma unroll
            for (int mt = 0; mt < 4; ++mt)
                av[mt] = *(const bf16x8*)(At + (wM * 64 + mt * 16 + lm) * 32 + qk);
            #pragma unroll
            for (int nt = 0; nt < 4; ++nt)
                bv[nt] = *(const bf16x8*)(Bt + (wN * 64 + nt * 16 + lm) * 32 + qk);
            #pragma unroll
            for (int mt = 0; mt < 4; ++mt)
                #pragma unroll
                for (int nt = 0; nt < 4; ++nt)
                    acc[mt][nt] = __builtin_amdgcn_mfma_f32_16x16x32_bf16(
                        av[mt], bv[nt], acc[mt][nt], 0, 0, 0);
        }

        const float* bias = (p == 0) ? bi : (p == 1 ? bfp : bc);
        #pragma unroll
        for (int nt = 0; nt < 4; ++nt) {
            int lcol = wN * 64 + nt * 16 + lm;
            float bb = bias[n0 + lcol];
            #pragma unroll
            for (int mt = 0; mt < 4; ++mt) {
                #pragma unroll
                for (int r = 0; r < 4; ++r) {
                    int lrow = wM * 64 + mt * 16 + (lane >> 4) * 4 + r;
                    float g = acc[mt][nt][r] + bb;
                    int li = lrow * 136 + lcol;
                    if (p == 0) {
                        stash[li] = f2bf(sigm(g));
                    } else if (p == 1) {
                        float iv = bf2f(stash[li]);
                        stash[li] = f2bf(sigm(iv - sigm(g)));
                    } else {
                        float al = bf2f(stash[li]);
                        float cv = mytanh(g);
                        size_t gi = (size_t)(m0 + lrow) * 1024 + (n0 + lcol);
                        out[gi] = al * cv + (1.f - al) * h[gi];
                    }
                }
            }
        }
    }
}

extern "C" void kernel_launch(void* const* d_in, const int* in_sizes, int n_in,
                              void* d_out, int out_size, void* d_ws, size_t ws_size,
                              hipStream_t stream) {
    const float* h   = (const float*)d_in[0];
    const float* x   = (const float*)d_in[1];
    const float* glo = (const float*)d_in[2];
    const float* Wi  = (const float*)d_in[3];
    const float* bi  = (const float*)d_in[4];
    const float* Wf  = (const float*)d_in[5];
    const float* bfp = (const float*)d_in[6];
    const float* Wc  = (const float*)d_in[7];
    const float* bc  = (const float*)d_in[8];
    float* out = (float*)d_out;

    const size_t szA = (size_t)8192 * 4096 * 2;   // 64 MiB bf16 A
    const size_t szW = (size_t)3072 * 4096 * 2;   // 24 MiB bf16 W

    if (ws_size >= szA + szW) {
        USHORT* Abf = (USHORT*)d_ws;
        USHORT* Wbf = (USHORT*)((char*)d_ws + szA);
        conv_all<<<8192 + 3072, 256, 0, stream>>>(h, x, glo, Wi, Wf, Wc, Abf, Wbf);
        gemm_fused<<<512, 512, 0, stream>>>(Abf, Wbf, bi, bfp, bc, h, out);
    } else {
        gemm3_noconv<<<dim3(8, 64), 256, 0, stream>>>(
            h, x, glo, Wi, Wf, Wc, bi, bfp, bc, out);
    }
}

// Round 5
// 393.889 us; speedup vs baseline: 1.1708x; 1.0012x over previous
//
#include <hip/hip_runtime.h>

typedef unsigned short USHORT;
typedef short bf16x8 __attribute__((ext_vector_type(8)));
typedef float f32x4 __attribute__((ext_vector_type(4)));

__device__ __forceinline__ USHORT f2bf(float f) {
    unsigned u = __float_as_uint(f);
    u += 0x7fffu + ((u >> 16) & 1u);   // RNE, no NaNs in this problem
    return (USHORT)(u >> 16);
}
__device__ __forceinline__ float bf2f(USHORT s) {
    return __uint_as_float(((unsigned)s) << 16);
}
__device__ __forceinline__ float sigm(float v) { return 1.f / (1.f + __expf(-v)); }
__device__ __forceinline__ float mytanh(float v) { return 1.f - 2.f / (__expf(2.f * v) + 1.f); }

using gcu32p = const unsigned int __attribute__((address_space(1))) *;
using lu32p  = unsigned int __attribute__((address_space(3))) *;
using lusp   = const USHORT __attribute__((address_space(3))) *;

__device__ __forceinline__ void load_lds16(const void* g, void* l) {
    __builtin_amdgcn_global_load_lds((gcu32p)g, (lu32p)l, 16, 0, 0);
}

// Inline-asm ds_read_b128 (no memory operand): keeps the compiler from
// inserting conservative vmcnt waits against in-flight global_load_lds DMA.
// Readiness is enforced by OUR explicit lgkmcnt/vmcnt/barrier schedule.
__device__ __forceinline__ bf16x8 ds_read16(const USHORT* p) {
    bf16x8 r;
    unsigned a = (unsigned)(unsigned long long)(lusp)p;   // generic -> LDS offset
    asm volatile("ds_read_b128 %0, %1" : "=v"(r) : "v"(a));
    return r;
}

// ---- conversion kernel: fp32 sources -> bf16 A [8192x4096] and W [3072x4096]
__global__ __launch_bounds__(256) void conv_all(const float* __restrict__ h,
                                                const float* __restrict__ x,
                                                const float* __restrict__ glo,
                                                const float* __restrict__ Wi,
                                                const float* __restrict__ Wf,
                                                const float* __restrict__ Wc,
                                                USHORT* __restrict__ A,
                                                USHORT* __restrict__ W) {
    int bid = blockIdx.x;
    const float* s;
    USHORT* dst;
    int idx;
    if (bid < 8192) {
        idx = (bid * 256 + threadIdx.x) * 16;      // [0, 8192*4096)
        int m = idx >> 12, k = idx & 4095;         // region boundaries %16==0
        if (k < 1024)      s = h   + (size_t)m * 1024 + k;
        else if (k < 3072) s = x   + (size_t)m * 2048 + (k - 1024);
        else               s = glo + (size_t)m * 1024 + (k - 3072);
        dst = A + idx;
    } else {
        idx = ((bid - 8192) * 256 + threadIdx.x) * 16;   // [0, 3072*4096)
        int n = idx >> 12, k = idx & 4095;
        const float* base = (n < 1024) ? Wi : (n < 2048 ? Wf : Wc);
        s = base + (size_t)(n & 1023) * 4096 + k;
        dst = W + idx;
    }
    float4 f0 = ((const float4*)s)[0];
    float4 f1 = ((const float4*)s)[1];
    float4 f2 = ((const float4*)s)[2];
    float4 f3 = ((const float4*)s)[3];
    union { USHORT us[16]; uint4 v[2]; } u;
    u.us[0]  = f2bf(f0.x); u.us[1]  = f2bf(f0.y); u.us[2]  = f2bf(f0.z); u.us[3]  = f2bf(f0.w);
    u.us[4]  = f2bf(f1.x); u.us[5]  = f2bf(f1.y); u.us[6]  = f2bf(f1.z); u.us[7]  = f2bf(f1.w);
    u.us[8]  = f2bf(f2.x); u.us[9]  = f2bf(f2.y); u.us[10] = f2bf(f2.z); u.us[11] = f2bf(f2.w);
    u.us[12] = f2bf(f3.x); u.us[13] = f2bf(f3.y); u.us[14] = f2bf(f3.z); u.us[15] = f2bf(f3.w);
    ((uint4*)dst)[0] = u.v[0];
    ((uint4*)dst)[1] = u.v[1];
}

// ============================================================================
// FUSED GEMM + LSTM gates, 2-blocks/CU TLP structure:
//   out[8192,1024] = alpha*tanh(c) + (1-alpha)*h,  alpha = sigm(sigm(i)-sigm(f))
//
// Diagnosis (r4): 1-block/CU barrier-lockstep serializes ds_read (2070 cyc)
// with MFMA (1862 cyc) at CU level -> 4464 cyc/tile, MfmaUtil 38%.
// Fix: BM=128, BN=192 (3 gates x 64 n), BK=64, 256 thr = 4 waves (1M x 4N,
// per-wave 128 x 48). LDS = dbuf (A 32K + B 48K) = exactly 80 KiB -> TWO
// blocks/CU; independent barriers phase-shift -> one block's MFMA overlaps
// the other's ds_read (m97/m114 mechanism).
// Per K-step: {issue 10 DMA (t+1, other buf); 22 asm ds_reads; lgkmcnt(11);
//   24 MFMA kh0; lgkmcnt(0); 24 MFMA kh1; vmcnt(0); s_barrier}.
//   WAR: t+1 DMA overwrites buf read at t-1, all reads drained (lgkmcnt(0))
//   before t-1's closing barrier. RAW: vmcnt(0)+barrier before buf read.
//   lgkmcnt counts DS ops only (global_load_lds is vmcnt-only, cf. m201).
// Granule XOR swizzle both sides (verified 0 bank conflicts in r1-r4; chunk
// rows are 16/32-aligned so the same gswz/koff0 formulas hold).
// Grid 1024 = 64 m x 16 n-slices, XCD-swizzled (per XCD: 2 slices, 3 MB of
// W -> L2-resident). Fused gate epilogue: same lane owns i,f,c of one (m,n).
// ============================================================================

#define ABUF 8192    // 128*64 elems per buffer
#define BBUF 12288   // 192*64 elems per buffer

template<int ISS>
__device__ __forceinline__ void kstep(const USHORT* aRd, const USHORT* bRd,
                                      USHORT* aWr, USHORT* bWr, int tid8,
                                      const USHORT* (&aG)[4], const USHORT* (&bG)[6],
                                      int koff0, f32x4 (&acc)[8][3]) {
    __builtin_amdgcn_sched_barrier(0);
    if (ISS) {    // stage tile t+1 into the other buffer (DMA, vmcnt-only)
        #pragma unroll
        for (int c = 0; c < 4; ++c) { load_lds16(aG[c], aWr + c * 2048 + tid8); aG[c] += 64; }
        #pragma unroll
        for (int c = 0; c < 6; ++c) { load_lds16(bG[c], bWr + c * 2048 + tid8); bG[c] += 64; }
    }
    // 22 ds_reads: kh0 group (11) then kh1 group (11); DS retires in order.
    bf16x8 a0[8], b0[3], a1[8], b1[3];
    #pragma unroll
    for (int mt = 0; mt < 8; ++mt) a0[mt] = ds_read16(aRd + mt * 1024 + koff0);
    #pragma unroll
    for (int g = 0; g < 3; ++g)    b0[g]  = ds_read16(bRd + g * 4096 + koff0);
    #pragma unroll
    for (int mt = 0; mt < 8; ++mt) a1[mt] = ds_read16(aRd + mt * 1024 + (koff0 ^ 32));
    #pragma unroll
    for (int g = 0; g < 3; ++g)    b1[g]  = ds_read16(bRd + g * 4096 + (koff0 ^ 32));
    asm volatile("s_waitcnt lgkmcnt(11)");     // kh0 group landed
    __builtin_amdgcn_sched_barrier(0);         // rule #18: pin MFMA after wait
    __builtin_amdgcn_s_setprio(1);
    #pragma unroll
    for (int mt = 0; mt < 8; ++mt)
        #pragma unroll
        for (int g = 0; g < 3; ++g)
            acc[mt][g] = __builtin_amdgcn_mfma_f32_16x16x32_bf16(
                a0[mt], b0[g], acc[mt][g], 0, 0, 0);
    __builtin_amdgcn_s_setprio(0);
    __builtin_amdgcn_sched_barrier(0);
    asm volatile("s_waitcnt lgkmcnt(0)");      // kh1 group landed
    __builtin_amdgcn_sched_barrier(0);
    __builtin_amdgcn_s_setprio(1);
    #pragma unroll
    for (int mt = 0; mt < 8; ++mt)
        #pragma unroll
        for (int g = 0; g < 3; ++g)
            acc[mt][g] = __builtin_amdgcn_mfma_f32_16x16x32_bf16(
                a1[mt], b1[g], acc[mt][g], 0, 0, 0);
    __builtin_amdgcn_s_setprio(0);
    __builtin_amdgcn_sched_barrier(0);
    if (ISS) asm volatile("s_waitcnt vmcnt(0)" ::: "memory");   // t+1 landed
    __builtin_amdgcn_s_barrier();
}

__global__ __launch_bounds__(256, 2) void gemm_fused(const USHORT* __restrict__ A,
                                                     const USHORT* __restrict__ B,
                                                     const float* __restrict__ bi,
                                                     const float* __restrict__ bfp,
                                                     const float* __restrict__ bc,
                                                     const float* __restrict__ h,
                                                     float* __restrict__ out) {
    __shared__ __align__(16) USHORT As[2 * ABUF];   // 32 KiB
    __shared__ __align__(16) USHORT Bs[2 * BBUF];   // 48 KiB  (total 80 -> 2 blk/CU)

    const int tid  = threadIdx.x;
    const int lane = tid & 63, wv = tid >> 6;
    // XCD-aware bijective swizzle (1024 % 8 == 0): per XCD 2 n-slices x 64 m.
    const int s  = (blockIdx.x & 7) * 128 + (blockIdx.x >> 3);
    const int m0 = (s & 63) * 128;
    const int n0 = (s >> 6) * 64;           // n-slice of H (16 slices)

    const int lm = lane & 15;
    const int gw = lane >> 4;                        // k-granule within 32-half
    const int koff0 = ((gw ^ (lm >> 1)) & 7) * 8;    // read-side swizzled granule (elems)
    const int tid8 = tid * 8;                        // staging LDS offset (elems)

    // staging: chunk = 32 rows x 64k (4 KiB); thread t -> row 32c + (t>>3),
    // LDS pos p = t&7, fetch global granule p ^ ((r>>1)&7) = gswz (r is
    // 32-aligned + t>>3, so (r>>1)&7 = (t>>4)&7 = 4*(wv&1) + (lane>>4)).
    const int gswz = ((lane & 7) ^ (4 * (wv & 1) + (lane >> 4))) & 7;
    const USHORT* aG[4];
    const USHORT* bG[6];
    #pragma unroll
    for (int c = 0; c < 4; ++c)
        aG[c] = A + (size_t)(m0 + c * 32 + (tid >> 3)) * 4096 + gswz * 8;
    #pragma unroll
    for (int c = 0; c < 6; ++c)   // B chunk c -> W rows (c>>1)*1024 + n0 + (c&1)*32 ...
        bG[c] = B + (size_t)((c >> 1) * 1024 + n0 + (c & 1) * 32 + (tid >> 3)) * 4096 + gswz * 8;

    f32x4 acc[8][3];
    #pragma unroll
    for (int a = 0; a < 8; ++a)
        #pragma unroll
        for (int b = 0; b < 3; ++b) {
            f32x4 z = {0.f, 0.f, 0.f, 0.f};
            acc[a][b] = z;
        }

    // read bases (include per-lane row offset); parity via named-pointer swap
    const int lmo = lm * 64;
    const int bro = (wv * 16 + lm) * 64;
    const USHORT* aRd  = As + lmo;          const USHORT* bRd  = Bs + bro;
    const USHORT* aRdN = As + ABUF + lmo;   const USHORT* bRdN = Bs + BBUF + bro;
    USHORT* aWr  = As + ABUF;               USHORT* bWr  = Bs + BBUF;
    USHORT* aWrN = As;                      USHORT* bWrN = Bs;

    // prologue: stage tile 0 into buf0; drain; barrier.
    #pragma unroll
    for (int c = 0; c < 4; ++c) { load_lds16(aG[c], As + c * 2048 + tid8); aG[c] += 64; }
    #pragma unroll
    for (int c = 0; c < 6; ++c) { load_lds16(bG[c], Bs + c * 2048 + tid8); bG[c] += 64; }
    asm volatile("s_waitcnt vmcnt(0)" ::: "memory");
    __builtin_amdgcn_s_barrier();

    for (int kt = 0; kt < 63; ++kt) {
        kstep<1>(aRd, bRd, aWr, bWr, tid8, aG, bG, koff0, acc);
        const USHORT* tp;
        tp = aRd; aRd = aRdN; aRdN = tp;
        tp = bRd; bRd = bRdN; bRdN = tp;
        USHORT* wp;
        wp = aWr; aWr = aWrN; aWrN = wp;
        wp = bWr; bWr = bWrN; bWrN = wp;
    }
    kstep<0>(aRd, bRd, aWr, bWr, tid8, aG, bG, koff0, acc);   // kt=63, no prefetch

    // fused epilogue: same lane holds i (g=0), f (g=1), c (g=2) for one
    // (row, n). C/D layout: col = lane&15, row = (lane>>4)*4 + r.
    const int nc = n0 + wv * 16 + lm;
    const float bbi = bi[nc], bbf = bfp[nc], bbc = bc[nc];
    #pragma unroll
    for (int mt = 0; mt < 8; ++mt) {
        #pragma unroll
        for (int r = 0; r < 4; ++r) {
            int lrow = mt * 16 + (lane >> 4) * 4 + r;
            size_t off = (size_t)(m0 + lrow) * 1024 + nc;
            float gi_ = acc[mt][0][r] + bbi;
            float gf_ = acc[mt][1][r] + bbf;
            float gc_ = acc[mt][2][r] + bbc;
            float iv = sigm(gi_);
            float fv = sigm(gf_);
            float al = sigm(iv - fv);
            float cv = mytanh(gc_);
            out[off] = al * cv + (1.f - al) * h[off];
        }
    }
}

// ---- fallback: fused 3-phase kernel, register-convert staging (only if ws too small)
__global__ __launch_bounds__(256) void gemm3_noconv(const float* __restrict__ h,
                                                    const float* __restrict__ x,
                                                    const float* __restrict__ glo,
                                                    const float* __restrict__ Wi,
                                                    const float* __restrict__ Wf,
                                                    const float* __restrict__ Wc,
                                                    const float* __restrict__ bi,
                                                    const float* __restrict__ bfp,
                                                    const float* __restrict__ bc,
                                                    float* __restrict__ out) {
    __shared__ USHORT At[128 * 32];
    __shared__ USHORT Bt[128 * 32];
    __shared__ USHORT stash[128 * 136];

    const int tid  = threadIdx.x;
    const int lane = tid & 63, wv = tid >> 6;
    const int n0 = blockIdx.x * 128;
    const int m0 = blockIdx.y * 128;
    const int wM = wv >> 1, wN = wv & 1;
    const int lm = lane & 15, qk = (lane >> 4) * 8;
    const int rowS = tid >> 1;
    const int colS = (tid & 1) * 16;

    for (int p = 0; p < 3; ++p) {
        f32x4 acc[4][4];
        #pragma unroll
        for (int a = 0; a < 4; ++a)
            #pragma unroll
            for (int b = 0; b < 4; ++b) {
                f32x4 z = {0.f, 0.f, 0.f, 0.f};
                acc[a][b] = z;
            }
        const float* Wg = (p == 0) ? Wi : (p == 1 ? Wf : Wc);

        for (int kt = 0; kt < 128; ++kt) {
            __syncthreads();
            int k = kt * 32 + colS;
            const float* s;
            if (k < 1024)      s = h   + (size_t)(m0 + rowS) * 1024 + k;
            else if (k < 3072) s = x   + (size_t)(m0 + rowS) * 2048 + (k - 1024);
            else               s = glo + (size_t)(m0 + rowS) * 1024 + (k - 3072);
            float4 f0 = ((const float4*)s)[0], f1 = ((const float4*)s)[1];
            float4 f2 = ((const float4*)s)[2], f3 = ((const float4*)s)[3];
            union { USHORT us[8]; uint4 v; } u0, u1;
            u0.us[0]=f2bf(f0.x); u0.us[1]=f2bf(f0.y); u0.us[2]=f2bf(f0.z); u0.us[3]=f2bf(f0.w);
            u0.us[4]=f2bf(f1.x); u0.us[5]=f2bf(f1.y); u0.us[6]=f2bf(f1.z); u0.us[7]=f2bf(f1.w);
            u1.us[0]=f2bf(f2.x); u1.us[1]=f2bf(f2.y); u1.us[2]=f2bf(f2.z); u1.us[3]=f2bf(f2.w);
            u1.us[4]=f2bf(f3.x); u1.us[5]=f2bf(f3.y); u1.us[6]=f2bf(f3.z); u1.us[7]=f2bf(f3.w);
            *(uint4*)(At + rowS * 32 + colS)     = u0.v;
            *(uint4*)(At + rowS * 32 + colS + 8) = u1.v;
            const float* sw = Wg + (size_t)(n0 + rowS) * 4096 + k;
            float4 w0 = ((const float4*)sw)[0], w1 = ((const float4*)sw)[1];
            float4 w2 = ((const float4*)sw)[2], w3 = ((const float4*)sw)[3];
            union { USHORT us[8]; uint4 v; } v0, v1;
            v0.us[0]=f2bf(w0.x); v0.us[1]=f2bf(w0.y); v0.us[2]=f2bf(w0.z); v0.us[3]=f2bf(w0.w);
            v0.us[4]=f2bf(w1.x); v0.us[5]=f2bf(w1.y); v0.us[6]=f2bf(w1.z); v0.us[7]=f2bf(w1.w);
            v1.us[0]=f2bf(w2.x); v1.us[1]=f2bf(w2.y); v1.us[2]=f2bf(w2.z); v1.us[3]=f2bf(w2.w);
            v1.us[4]=f2bf(w3.x); v1.us[5]=f2bf(w3.y); v1.us[6]=f2bf(w3.z); v1.us[7]=f2bf(w3.w);
            *(uint4*)(Bt + rowS * 32 + colS)     = v0.v;
            *(uint4*)(Bt + rowS * 32 + colS + 8) = v1.v;
            __syncthreads();

            bf16x8 av[4], bv[4];
            #pragma unroll
            for (int mt = 0; mt < 4; ++mt)
                av[mt] = *(const bf16x8*)(At + (wM * 64 + mt * 16 + lm) * 32 + qk);
            #pragma unroll
            for (int nt = 0; nt < 4; ++nt)
                bv[nt] = *(const bf16x8*)(Bt + (wN * 64 + nt * 16 + lm) * 32 + qk);
            #pragma unroll
            for (int mt = 0; mt < 4; ++mt)
                #pragma unroll
                for (int nt = 0; nt < 4; ++nt)
                    acc[mt][nt] = __builtin_amdgcn_mfma_f32_16x16x32_bf16(
                        av[mt], bv[nt], acc[mt][nt], 0, 0, 0);
        }

        const float* bias = (p == 0) ? bi : (p == 1 ? bfp : bc);
        #pragma unroll
        for (int nt = 0; nt < 4; ++nt) {
            int lcol = wN * 64 + nt * 16 + lm;
            float bb = bias[n0 + lcol];
            #pragma unroll
            for (int mt = 0; mt < 4; ++mt) {
                #pragma unroll
                for (int r = 0; r < 4; ++r) {
                    int lrow = wM * 64 + mt * 16 + (lane >> 4) * 4 + r;
                    float g = acc[mt][nt][r] + bb;
                    int li = lrow * 136 + lcol;
                    if (p == 0) {
                        stash[li] = f2bf(sigm(g));
                    } else if (p == 1) {
                        float iv = bf2f(stash[li]);
                        stash[li] = f2bf(sigm(iv - sigm(g)));
                    } else {
                        float al = bf2f(stash[li]);
                        float cv = mytanh(g);
                        size_t gi = (size_t)(m0 + lrow) * 1024 + (n0 + lcol);
                        out[gi] = al * cv + (1.f - al) * h[gi];
                    }
                }
            }
        }
    }
}

extern "C" void kernel_launch(void* const* d_in, const int* in_sizes, int n_in,
                              void* d_out, int out_size, void* d_ws, size_t ws_size,
                              hipStream_t stream) {
    const float* h   = (const float*)d_in[0];
    const float* x   = (const float*)d_in[1];
    const float* glo = (const float*)d_in[2];
    const float* Wi  = (const float*)d_in[3];
    const float* bi  = (const float*)d_in[4];
    const float* Wf  = (const float*)d_in[5];
    const float* bfp = (const float*)d_in[6];
    const float* Wc  = (const float*)d_in[7];
    const float* bc  = (const float*)d_in[8];
    float* out = (float*)d_out;

    const size_t szA = (size_t)8192 * 4096 * 2;   // 64 MiB bf16 A
    const size_t szW = (size_t)3072 * 4096 * 2;   // 24 MiB bf16 W

    if (ws_size >= szA + szW) {
        USHORT* Abf = (USHORT*)d_ws;
        USHORT* Wbf = (USHORT*)((char*)d_ws + szA);
        conv_all<<<8192 + 3072, 256, 0, stream>>>(h, x, glo, Wi, Wf, Wc, Abf, Wbf);
        gemm_fused<<<1024, 256, 0, stream>>>(Abf, Wbf, bi, bfp, bc, h, out);
    } else {
        gemm3_noconv<<<dim3(8, 64), 256, 0, stream>>>(
            h, x, glo, Wi, Wf, Wc, bi, bfp, bc, out);
    }
}